// Round 6
// baseline (3202.467 us; speedup 1.0000x reference)
//
#include <hip/hip_runtime.h>
#include <math.h>

#define N_NODES 100000
#define N_EDGES 1600000
#define SCAN_BS 256

__device__ __forceinline__ float sigmoidf_(float x){ return 1.f/(1.f + expf(-x)); }
__device__ __forceinline__ float eluf_(float x){ return x > 0.f ? x : expm1f(x); }

__device__ __forceinline__ float fma4_(float acc, float4 a, float4 b){
  return fmaf(a.x,b.x, fmaf(a.y,b.y, fmaf(a.z,b.z, fmaf(a.w,b.w,acc))));
}

// ---------------- CSR build (dst-sorted edge lists) ----------------
__global__ void zero_counts(int* cnt, int* cur, int n){
  int i = blockIdx.x*blockDim.x + threadIdx.x;
  if (i < n){ cnt[i]=0; cur[i]=0; }
}
__global__ void count_kernel(const int* __restrict__ ei, int* __restrict__ cnt, int e){
  int i = blockIdx.x*blockDim.x + threadIdx.x;
  if (i < e) atomicAdd(&cnt[ei[N_EDGES + i]], 1);
}
__global__ void scan1_kernel(const int* __restrict__ cnt, int* __restrict__ pre,
                             int* __restrict__ bsum, int n){
  __shared__ int sh[SCAN_BS];
  int t = threadIdx.x, gi = blockIdx.x*SCAN_BS + t;
  int v = (gi < n) ? cnt[gi] : 0;
  sh[t] = v;
  __syncthreads();
  for (int off=1; off<SCAN_BS; off<<=1){
    int u = (t>=off)?sh[t-off]:0;
    __syncthreads();
    sh[t] += u;
    __syncthreads();
  }
  if (gi < n) pre[gi] = sh[t] - v;
  if (t == SCAN_BS-1) bsum[blockIdx.x] = sh[t];
}
__global__ void scan2_kernel(int* __restrict__ bsum, int nb){
  __shared__ int sh[1024];
  int t = threadIdx.x;
  int v = (t < nb) ? bsum[t] : 0;
  sh[t] = v;
  __syncthreads();
  for (int off=1; off<1024; off<<=1){
    int u = (t>=off)?sh[t-off]:0;
    __syncthreads();
    sh[t] += u;
    __syncthreads();
  }
  if (t < nb) bsum[t] = sh[t] - v;
}
__global__ void scan3_kernel(const int* __restrict__ pre, const int* __restrict__ bsum,
                             int* __restrict__ row_start, int n){
  int i = blockIdx.x*blockDim.x + threadIdx.x;
  if (i < n) row_start[i] = pre[i] + bsum[i/SCAN_BS];
  if (i == 0) row_start[n] = N_EDGES;
}
__global__ void scatter_kernel(const int* __restrict__ ei, const float* __restrict__ ea,
    const int* __restrict__ row_start, int* __restrict__ cur,
    int* __restrict__ ssrc, float* __restrict__ sew, int e){
  int i = blockIdx.x*blockDim.x + threadIdx.x;
  if (i < e){
    int d = ei[N_EDGES + i];
    int p = row_start[d] + atomicAdd(&cur[d], 1);
    ssrc[p] = ei[i];
    sew[p] = ea[i];
  }
}

// ---------------- elementwise ----------------
__global__ void pad_x_kernel(const float* __restrict__ x, float* __restrict__ h, int n){
  int i = blockIdx.x*blockDim.x + threadIdx.x;
  if (i < n*32){
    int node = i >> 5, c = i & 31;
    h[i] = (c < 16) ? x[node*16 + c] : 0.f;
  }
}
__global__ void transition_kernel(const float* __restrict__ h1, float* __restrict__ h2, int n){
  int i = blockIdx.x*blockDim.x + threadIdx.x;
  if (i < n*64){
    int node = i >> 6, c = i & 63;
    h2[i] = (c < 32) ? eluf_(h1[node*32 + c]) : 0.f;
  }
}

// ---------------- m = h @ W  (C x C): k4-blocked, b128 LDS reads ----------------
template<int C, int NT>
__global__ __launch_bounds__(256) void mgemm_kernel(const float* __restrict__ hin,
    const float* __restrict__ W, float* __restrict__ mout, int n){
  constexpr int HC = C/2;
  constexpr int G = 256/HC;
  constexpr int NB = G*NT;
  constexpr int K4 = C/4;
  constexpr int WST = C*4 + 4;           // dwords per k4 block (pad -> write 2-way only)
  __shared__ __align__(16) float Wl4[K4*WST];
  __shared__ __align__(16) float stage[NB*C];
  int tid = threadIdx.x;
  int cc = tid % HC, g = tid / HC;
  int base = blockIdx.x * NB;
  // weights: W[k*C+c] -> Wl4[(k>>2)*WST + c*4 + (k&3)]
  for (int idx=tid; idx<C*C; idx+=256){
    int k = idx / C, c = idx % C;
    Wl4[(k>>2)*WST + c*4 + (k&3)] = W[idx];
  }
  // stage fill: vectorized b128
  for (int i4=tid; i4<NB*C/4; i4+=256){
    int node = base + (i4*4)/C;
    ((float4*)stage)[i4] = (node < n) ? *((const float4*)(hin + (size_t)node*C + (i4*4)%C))
                                      : float4{0.f,0.f,0.f,0.f};
  }
  __syncthreads();
  float acc0[NT], acc1[NT];
  #pragma unroll
  for(int j=0;j<NT;j++){acc0[j]=0.f;acc1[j]=0.f;}
  const float* wb = Wl4 + cc*4;
  const float* sb = stage + g*NT*C;
  #pragma unroll
  for (int k4=0;k4<K4;k4++){
    float4 w0 = *(const float4*)(wb + k4*WST);
    float4 w1 = *(const float4*)(wb + k4*WST + HC*4);
    #pragma unroll
    for (int j=0;j<NT;j++){
      float4 a = *(const float4*)(sb + j*C + k4*4);
      acc0[j] = fma4_(acc0[j], a, w0);
      acc1[j] = fma4_(acc1[j], a, w1);
    }
  }
  #pragma unroll
  for (int j=0;j<NT;j++){
    int node = base + g*NT + j;
    if (node < n){
      mout[(size_t)node*C + cc]      = acc0[j];
      mout[(size_t)node*C + cc + HC] = acc1[j];
    }
  }
}

// ---------------- agg[n][c] = max over incoming edges of m[src][c]*ew, else 0 ----------------
template<int C>
__global__ void agg_kernel(const float* __restrict__ m, const int* __restrict__ row_start,
    const int* __restrict__ ssrc, const float* __restrict__ sew,
    float* __restrict__ agg, int n_nodes){
  int gid = blockIdx.x*blockDim.x + threadIdx.x;
  int nn = gid / C, c = gid % C;
  if (nn >= n_nodes) return;
  int s = row_start[nn], e = row_start[nn+1];
  float acc = -__builtin_inff();
  for (int i=s;i<e;i++){
    int src = ssrc[i];
    float w = sew[i];
    acc = fmaxf(acc, m[(size_t)src*C + c]*w);
  }
  agg[(size_t)nn*C+c] = (e > s) ? acc : 0.f;
}

// ---------------- fused GRU cell: k4-blocked weights, b128 LDS reads ----------
// WT4 layout: Wih[r*C+k] -> WT4[(k>>2)*WST + r*4 + (k&3)]  (fill is contiguous b128:
// 4 consecutive k, same r). Pad WST=R*4+4 -> write banks (k+4r)%32: 2-way = free.
// Lane c reads gate rows {c, c+C, c+2C} as 3x float4 at immediate offsets.
template<int C, int NT>
__global__ __launch_bounds__(256) void gru_kernel(
    const float* __restrict__ agg, const float* __restrict__ hin,
    const float* __restrict__ Wih, const float* __restrict__ Whh,
    const float* __restrict__ bih, const float* __restrict__ bhh,
    float* __restrict__ hout, int n_nodes){
  constexpr int G  = 256 / C;
  constexpr int NB = G * NT;
  constexpr int R  = 3 * C;
  constexpr int K4 = C/4;
  constexpr int WST = R*4 + 4;
  __shared__ __align__(16) float WT4[K4*WST];
  __shared__ __align__(16) float stage[NB*C];
  int tid = threadIdx.x;
  int c = tid % C;
  int g = tid / C;
  int base = blockIdx.x * NB;

  float giR[NT], giZ[NT], giN[NT];
  float ghR[NT], ghZ[NT], ghN[NT];

  const float* wb = WT4 + c*4;
  const float* sb = stage + g*NT*C;

  // ---- phase 1: gi = agg @ Wih^T + bih ----
  for (int i4=tid; i4<C*R/4; i4+=256){
    float4 v = ((const float4*)Wih)[i4];
    int idx = i4*4;
    int r = idx / C, k = idx % C;              // k multiple of 4
    *(float4*)(WT4 + (k>>2)*WST + r*4) = v;
  }
  for (int i4=tid; i4<NB*C/4; i4+=256){
    int node = base + (i4*4)/C;
    ((float4*)stage)[i4] = (node < n_nodes) ? *((const float4*)(agg + (size_t)node*C + (i4*4)%C))
                                            : float4{0.f,0.f,0.f,0.f};
  }
  __syncthreads();
  {
    float b0 = bih[c], b1 = bih[c+C], b2 = bih[c+2*C];
    #pragma unroll
    for (int j=0;j<NT;j++){ giR[j]=b0; giZ[j]=b1; giN[j]=b2; }
    #pragma unroll
    for (int k4=0;k4<K4;k4++){
      float4 wR = *(const float4*)(wb + k4*WST);
      float4 wZ = *(const float4*)(wb + k4*WST + C*4);
      float4 wN = *(const float4*)(wb + k4*WST + 2*C*4);
      #pragma unroll
      for (int j=0;j<NT;j++){
        float4 a = *(const float4*)(sb + j*C + k4*4);
        giR[j] = fma4_(giR[j], a, wR);
        giZ[j] = fma4_(giZ[j], a, wZ);
        giN[j] = fma4_(giN[j], a, wN);
      }
    }
  }
  __syncthreads();
  // ---- phase 2: gh = h @ Whh^T + bhh ----
  for (int i4=tid; i4<C*R/4; i4+=256){
    float4 v = ((const float4*)Whh)[i4];
    int idx = i4*4;
    int r = idx / C, k = idx % C;
    *(float4*)(WT4 + (k>>2)*WST + r*4) = v;
  }
  for (int i4=tid; i4<NB*C/4; i4+=256){
    int node = base + (i4*4)/C;
    ((float4*)stage)[i4] = (node < n_nodes) ? *((const float4*)(hin + (size_t)node*C + (i4*4)%C))
                                            : float4{0.f,0.f,0.f,0.f};
  }
  __syncthreads();
  {
    float b0 = bhh[c], b1 = bhh[c+C], b2 = bhh[c+2*C];
    #pragma unroll
    for (int j=0;j<NT;j++){ ghR[j]=b0; ghZ[j]=b1; ghN[j]=b2; }
    #pragma unroll
    for (int k4=0;k4<K4;k4++){
      float4 wR = *(const float4*)(wb + k4*WST);
      float4 wZ = *(const float4*)(wb + k4*WST + C*4);
      float4 wN = *(const float4*)(wb + k4*WST + 2*C*4);
      #pragma unroll
      for (int j=0;j<NT;j++){
        float4 a = *(const float4*)(sb + j*C + k4*4);
        ghR[j] = fma4_(ghR[j], a, wR);
        ghZ[j] = fma4_(ghZ[j], a, wZ);
        ghN[j] = fma4_(ghN[j], a, wN);
      }
    }
  }
  // ---- gates ----
  #pragma unroll
  for (int j=0;j<NT;j++){
    int node = base + g*NT + j;
    if (node < n_nodes){
      float h  = stage[(g*NT+j)*C + c];
      float r  = sigmoidf_(giR[j] + ghR[j]);
      float z  = sigmoidf_(giZ[j] + ghZ[j]);
      float nn = tanhf(giN[j] + r*ghN[j]);
      hout[(size_t)node*C + c] = (1.f - z)*nn + z*h;
    }
  }
}

// ---------------- head: elu -> fc1 -> elu -> fc2 -> log_softmax ----------------
__global__ __launch_bounds__(256) void head_kernel(const float* __restrict__ h2,
   const float* __restrict__ fc1w, const float* __restrict__ fc1b,
   const float* __restrict__ fc2w, const float* __restrict__ fc2b,
   float* __restrict__ out, int n){
  __shared__ __align__(16) float W1l[128*64];
  __shared__ float W2l[10*128];
  __shared__ float b1l[128];
  __shared__ float b2l[10];
  int tid = threadIdx.x;
  for (int idx=tid; idx<128*64; idx+=256) W1l[idx]=fc1w[idx];
  for (int idx=tid; idx<10*128; idx+=256) W2l[idx]=fc2w[idx];
  if (tid<128) b1l[tid]=fc1b[tid];
  if (tid<10)  b2l[tid]=fc2b[tid];
  __syncthreads();
  int n0 = blockIdx.x*512 + tid;
  int n1 = n0 + 256;
  bool v0 = n0 < n, v1 = n1 < n;
  float h0[64], h1[64];
  #pragma unroll
  for (int k=0;k<64;k++){
    h0[k] = v0 ? eluf_(h2[(size_t)n0*64+k]) : 0.f;
    h1[k] = v1 ? eluf_(h2[(size_t)n1*64+k]) : 0.f;
  }
  float lg0[10], lg1[10];
  #pragma unroll
  for (int c=0;c<10;c++){ lg0[c]=b2l[c]; lg1[c]=b2l[c]; }
  for (int j=0;j<128;j++){
    float s0 = b1l[j], s1 = b1l[j];
    const float4* w4 = (const float4*)(W1l + j*64);
    #pragma unroll
    for (int q=0;q<16;q++){
      float4 w = w4[q];
      s0 = fmaf(h0[4*q],w.x,fmaf(h0[4*q+1],w.y,fmaf(h0[4*q+2],w.z,fmaf(h0[4*q+3],w.w,s0))));
      s1 = fmaf(h1[4*q],w.x,fmaf(h1[4*q+1],w.y,fmaf(h1[4*q+2],w.z,fmaf(h1[4*q+3],w.w,s1))));
    }
    float e0 = eluf_(s0), e1 = eluf_(s1);
    #pragma unroll
    for (int c=0;c<10;c++){
      float w2 = W2l[c*128+j];
      lg0[c] = fmaf(e0, w2, lg0[c]);
      lg1[c] = fmaf(e1, w2, lg1[c]);
    }
  }
  if (v0){
    float mx = lg0[0];
    #pragma unroll
    for (int c=1;c<10;c++) mx = fmaxf(mx, lg0[c]);
    float s = 0.f;
    #pragma unroll
    for (int c=0;c<10;c++) s += expf(lg0[c]-mx);
    float lse = mx + logf(s);
    #pragma unroll
    for (int c=0;c<10;c++) out[(size_t)n0*10+c] = lg0[c]-lse;
  }
  if (v1){
    float mx = lg1[0];
    #pragma unroll
    for (int c=1;c<10;c++) mx = fmaxf(mx, lg1[c]);
    float s = 0.f;
    #pragma unroll
    for (int c=0;c<10;c++) s += expf(lg1[c]-mx);
    float lse = mx + logf(s);
    #pragma unroll
    for (int c=0;c<10;c++) out[(size_t)n1*10+c] = lg1[c]-lse;
  }
}

extern "C" void kernel_launch(void* const* d_in, const int* in_sizes, int n_in,
                              void* d_out, int out_size, void* d_ws, size_t ws_size,
                              hipStream_t stream){
  const float* x    = (const float*)d_in[0];
  const int*   ei   = (const int*)  d_in[1];
  const float* ea   = (const float*)d_in[2];
  const float* W1   = (const float*)d_in[3];
  const float* Wih1 = (const float*)d_in[4];
  const float* Whh1 = (const float*)d_in[5];
  const float* bih1 = (const float*)d_in[6];
  const float* bhh1 = (const float*)d_in[7];
  const float* W2   = (const float*)d_in[8];
  const float* Wih2 = (const float*)d_in[9];
  const float* Whh2 = (const float*)d_in[10];
  const float* bih2 = (const float*)d_in[11];
  const float* bhh2 = (const float*)d_in[12];
  const float* fc1w = (const float*)d_in[13];
  const float* fc1b = (const float*)d_in[14];
  const float* fc2w = (const float*)d_in[15];
  const float* fc2b = (const float*)d_in[16];
  float* outp = (float*)d_out;

  char* ws = (char*)d_ws;
  size_t off = 0;
  auto alloc = [&](size_t bytes)->void*{
    void* p = ws + off;
    off += (bytes + 255) & ~size_t(255);
    return p;
  };
  float* hA        = (float*)alloc(sizeof(float)*N_NODES*64);
  float* hB        = (float*)alloc(sizeof(float)*N_NODES*64);
  float* mB        = (float*)alloc(sizeof(float)*N_NODES*64);
  float* aggB      = (float*)alloc(sizeof(float)*N_NODES*64);
  int*   row_start = (int*)  alloc(sizeof(int)*(N_NODES+1));
  int*   cnt       = (int*)  alloc(sizeof(int)*N_NODES);
  int*   cur       = (int*)  alloc(sizeof(int)*N_NODES);
  int*   pre       = (int*)  alloc(sizeof(int)*N_NODES);
  int*   bsum      = (int*)  alloc(sizeof(int)*1024);
  int*   ssrc      = (int*)  alloc(sizeof(int)*N_EDGES);
  float* sew       = (float*)alloc(sizeof(float)*N_EDGES);
  (void)ws_size; (void)in_sizes; (void)n_in; (void)out_size;

  const int n = N_NODES, e = N_EDGES;
  const int nb = (n + SCAN_BS - 1)/SCAN_BS;

  zero_counts<<<(n+255)/256,256,0,stream>>>(cnt, cur, n);
  count_kernel<<<(e+255)/256,256,0,stream>>>(ei, cnt, e);
  scan1_kernel<<<nb,SCAN_BS,0,stream>>>(cnt, pre, bsum, n);
  scan2_kernel<<<1,1024,0,stream>>>(bsum, nb);
  scan3_kernel<<<(n+255)/256,256,0,stream>>>(pre, bsum, row_start, n);
  scatter_kernel<<<(e+255)/256,256,0,stream>>>(ei, ea, row_start, cur, ssrc, sew, e);

  // layer 1 (C=32): NB = 8*8 = 64 nodes/block
  pad_x_kernel<<<(n*32+255)/256,256,0,stream>>>(x, hA, n);
  for (int i=0;i<3;i++){
    mgemm_kernel<32,8><<<(n+127)/128,256,0,stream>>>(hA, W1 + i*32*32, mB, n);
    agg_kernel<32><<<((long long)n*32+255)/256,256,0,stream>>>(mB, row_start, ssrc, sew, aggB, n);
    gru_kernel<32,8><<<(n+63)/64,256,0,stream>>>(aggB, hA, Wih1, Whh1, bih1, bhh1, hA, n);
  }

  transition_kernel<<<(n*64+255)/256,256,0,stream>>>(hA, hB, n);

  // layer 2 (C=64): NB = 4*8 = 32 nodes/block
  for (int i=0;i<3;i++){
    mgemm_kernel<64,8><<<(n+63)/64,256,0,stream>>>(hB, W2 + i*64*64, mB, n);
    agg_kernel<64><<<((long long)n*64+255)/256,256,0,stream>>>(mB, row_start, ssrc, sew, aggB, n);
    gru_kernel<64,8><<<(n+31)/32,256,0,stream>>>(aggB, hB, Wih2, Whh2, bih2, bhh2, hB, n);
  }

  head_kernel<<<(n+511)/512,256,0,stream>>>(hB, fc1w, fc1b, fc2w, fc2b, outp, n);
}

// Round 7
// 1334.929 us; speedup vs baseline: 2.3990x; 2.3990x over previous
//
#include <hip/hip_runtime.h>
#include <math.h>

#define N_NODES 100000
#define N_EDGES 1600000
#define SCAN_BS 256

__device__ __forceinline__ float sigmoidf_(float x){ return 1.f/(1.f + expf(-x)); }
__device__ __forceinline__ float eluf_(float x){ return x > 0.f ? x : expm1f(x); }

__device__ __forceinline__ float fma4_(float acc, float4 a, float4 b){
  return fmaf(a.x,b.x, fmaf(a.y,b.y, fmaf(a.z,b.z, fmaf(a.w,b.w,acc))));
}

// ---------------- CSR build (dst-sorted edge lists) ----------------
__global__ void zero_counts(int* cnt, int* cur, int n){
  int i = blockIdx.x*blockDim.x + threadIdx.x;
  if (i < n){ cnt[i]=0; cur[i]=0; }
}
__global__ void count_kernel(const int* __restrict__ ei, int* __restrict__ cnt, int e){
  int i = blockIdx.x*blockDim.x + threadIdx.x;
  if (i < e) atomicAdd(&cnt[ei[N_EDGES + i]], 1);
}
__global__ void scan1_kernel(const int* __restrict__ cnt, int* __restrict__ pre,
                             int* __restrict__ bsum, int n){
  __shared__ int sh[SCAN_BS];
  int t = threadIdx.x, gi = blockIdx.x*SCAN_BS + t;
  int v = (gi < n) ? cnt[gi] : 0;
  sh[t] = v;
  __syncthreads();
  for (int off=1; off<SCAN_BS; off<<=1){
    int u = (t>=off)?sh[t-off]:0;
    __syncthreads();
    sh[t] += u;
    __syncthreads();
  }
  if (gi < n) pre[gi] = sh[t] - v;
  if (t == SCAN_BS-1) bsum[blockIdx.x] = sh[t];
}
__global__ void scan2_kernel(int* __restrict__ bsum, int nb){
  __shared__ int sh[1024];
  int t = threadIdx.x;
  int v = (t < nb) ? bsum[t] : 0;
  sh[t] = v;
  __syncthreads();
  for (int off=1; off<1024; off<<=1){
    int u = (t>=off)?sh[t-off]:0;
    __syncthreads();
    sh[t] += u;
    __syncthreads();
  }
  if (t < nb) bsum[t] = sh[t] - v;
}
__global__ void scan3_kernel(const int* __restrict__ pre, const int* __restrict__ bsum,
                             int* __restrict__ row_start, int n){
  int i = blockIdx.x*blockDim.x + threadIdx.x;
  if (i < n) row_start[i] = pre[i] + bsum[i/SCAN_BS];
  if (i == 0) row_start[n] = N_EDGES;
}
__global__ void scatter_kernel(const int* __restrict__ ei, const float* __restrict__ ea,
    const int* __restrict__ row_start, int* __restrict__ cur,
    int* __restrict__ ssrc, float* __restrict__ sew, int e){
  int i = blockIdx.x*blockDim.x + threadIdx.x;
  if (i < e){
    int d = ei[N_EDGES + i];
    int p = row_start[d] + atomicAdd(&cur[d], 1);
    ssrc[p] = ei[i];
    sew[p] = ea[i];
  }
}

// ---------------- elementwise ----------------
__global__ void pad_x_kernel(const float* __restrict__ x, float* __restrict__ h, int n){
  int i = blockIdx.x*blockDim.x + threadIdx.x;
  if (i < n*32){
    int node = i >> 5, c = i & 31;
    h[i] = (c < 16) ? x[node*16 + c] : 0.f;
  }
}
__global__ void transition_kernel(const float* __restrict__ h1, float* __restrict__ h2, int n){
  int i = blockIdx.x*blockDim.x + threadIdx.x;
  if (i < n*64){
    int node = i >> 6, c = i & 63;
    h2[i] = (c < 32) ? eluf_(h1[node*32 + c]) : 0.f;
  }
}

// ---------------- m = h @ W  (C x C): k4-blocked, b128 LDS reads ----------------
template<int C, int NT>
__global__ __launch_bounds__(256) void mgemm_kernel(const float* __restrict__ hin,
    const float* __restrict__ W, float* __restrict__ mout, int n){
  constexpr int HC = C/2;
  constexpr int G = 256/HC;
  constexpr int NB = G*NT;
  constexpr int K4 = C/4;
  constexpr int WST = C*4 + 4;           // dwords per k4 block (pad -> write 2-way only)
  __shared__ __align__(16) float Wl4[K4*WST];
  __shared__ __align__(16) float stage[NB*C];
  int tid = threadIdx.x;
  int cc = tid % HC, g = tid / HC;
  int base = blockIdx.x * NB;
  // weights: W[k*C+c] -> Wl4[(k>>2)*WST + c*4 + (k&3)]
  for (int idx=tid; idx<C*C; idx+=256){
    int k = idx / C, c = idx % C;
    Wl4[(k>>2)*WST + c*4 + (k&3)] = W[idx];
  }
  // stage fill: vectorized b128
  for (int i4=tid; i4<NB*C/4; i4+=256){
    int node = base + (i4*4)/C;
    ((float4*)stage)[i4] = (node < n) ? *((const float4*)(hin + (size_t)node*C + (i4*4)%C))
                                      : float4{0.f,0.f,0.f,0.f};
  }
  __syncthreads();
  float acc0[NT], acc1[NT];
  #pragma unroll
  for(int j=0;j<NT;j++){acc0[j]=0.f;acc1[j]=0.f;}
  const float* wb = Wl4 + cc*4;
  const float* sb = stage + g*NT*C;
  #pragma unroll 2
  for (int k4=0;k4<K4;k4++){
    float4 w0 = *(const float4*)(wb + k4*WST);
    float4 w1 = *(const float4*)(wb + k4*WST + HC*4);
    #pragma unroll
    for (int j=0;j<NT;j++){
      float4 a = *(const float4*)(sb + j*C + k4*4);
      acc0[j] = fma4_(acc0[j], a, w0);
      acc1[j] = fma4_(acc1[j], a, w1);
    }
  }
  #pragma unroll
  for (int j=0;j<NT;j++){
    int node = base + g*NT + j;
    if (node < n){
      mout[(size_t)node*C + cc]      = acc0[j];
      mout[(size_t)node*C + cc + HC] = acc1[j];
    }
  }
}

// ---------------- agg[n][c] = max over incoming edges of m[src][c]*ew, else 0 ----------------
template<int C>
__global__ void agg_kernel(const float* __restrict__ m, const int* __restrict__ row_start,
    const int* __restrict__ ssrc, const float* __restrict__ sew,
    float* __restrict__ agg, int n_nodes){
  int gid = blockIdx.x*blockDim.x + threadIdx.x;
  int nn = gid / C, c = gid % C;
  if (nn >= n_nodes) return;
  int s = row_start[nn], e = row_start[nn+1];
  float acc = -__builtin_inff();
  for (int i=s;i<e;i++){
    int src = ssrc[i];
    float w = sew[i];
    acc = fmaxf(acc, m[(size_t)src*C + c]*w);
  }
  agg[(size_t)nn*C+c] = (e > s) ? acc : 0.f;
}

// ---------------- fused GRU cell: k4-blocked weights, b128 LDS reads ----------
// WT4 layout: Wih[r*C+k] -> WT4[(k>>2)*WST + r*4 + (k&3)]  (fill is contiguous b128:
// 4 consecutive k, same r). Pad WST=R*4+4 -> write banks (k+4r)%32: 2-way = free.
// Lane c reads gate rows {c, c+C, c+2C} as 3x float4 at immediate offsets.
// K4 loop capped at unroll 2 (R6 lesson: full unroll -> 256 VGPR + 765MB spill).
template<int C, int NT>
__global__ __launch_bounds__(256) void gru_kernel(
    const float* __restrict__ agg, const float* __restrict__ hin,
    const float* __restrict__ Wih, const float* __restrict__ Whh,
    const float* __restrict__ bih, const float* __restrict__ bhh,
    float* __restrict__ hout, int n_nodes){
  constexpr int G  = 256 / C;
  constexpr int NB = G * NT;
  constexpr int R  = 3 * C;
  constexpr int K4 = C/4;
  constexpr int WST = R*4 + 4;
  __shared__ __align__(16) float WT4[K4*WST];
  __shared__ __align__(16) float stage[NB*C];
  int tid = threadIdx.x;
  int c = tid % C;
  int g = tid / C;
  int base = blockIdx.x * NB;

  float giR[NT], giZ[NT], giN[NT];
  float ghR[NT], ghZ[NT], ghN[NT];

  const float* wb = WT4 + c*4;
  const float* sb = stage + g*NT*C;

  // ---- phase 1: gi = agg @ Wih^T + bih ----
  for (int i4=tid; i4<C*R/4; i4+=256){
    float4 v = ((const float4*)Wih)[i4];
    int idx = i4*4;
    int r = idx / C, k = idx % C;              // k multiple of 4
    *(float4*)(WT4 + (k>>2)*WST + r*4) = v;
  }
  for (int i4=tid; i4<NB*C/4; i4+=256){
    int node = base + (i4*4)/C;
    ((float4*)stage)[i4] = (node < n_nodes) ? *((const float4*)(agg + (size_t)node*C + (i4*4)%C))
                                            : float4{0.f,0.f,0.f,0.f};
  }
  __syncthreads();
  {
    float b0 = bih[c], b1 = bih[c+C], b2 = bih[c+2*C];
    #pragma unroll
    for (int j=0;j<NT;j++){ giR[j]=b0; giZ[j]=b1; giN[j]=b2; }
    #pragma unroll 2
    for (int k4=0;k4<K4;k4++){
      float4 wR = *(const float4*)(wb + k4*WST);
      float4 wZ = *(const float4*)(wb + k4*WST + C*4);
      float4 wN = *(const float4*)(wb + k4*WST + 2*C*4);
      #pragma unroll
      for (int j=0;j<NT;j++){
        float4 a = *(const float4*)(sb + j*C + k4*4);
        giR[j] = fma4_(giR[j], a, wR);
        giZ[j] = fma4_(giZ[j], a, wZ);
        giN[j] = fma4_(giN[j], a, wN);
      }
    }
  }
  __syncthreads();
  // ---- phase 2: gh = h @ Whh^T + bhh ----
  for (int i4=tid; i4<C*R/4; i4+=256){
    float4 v = ((const float4*)Whh)[i4];
    int idx = i4*4;
    int r = idx / C, k = idx % C;
    *(float4*)(WT4 + (k>>2)*WST + r*4) = v;
  }
  for (int i4=tid; i4<NB*C/4; i4+=256){
    int node = base + (i4*4)/C;
    ((float4*)stage)[i4] = (node < n_nodes) ? *((const float4*)(hin + (size_t)node*C + (i4*4)%C))
                                            : float4{0.f,0.f,0.f,0.f};
  }
  __syncthreads();
  {
    float b0 = bhh[c], b1 = bhh[c+C], b2 = bhh[c+2*C];
    #pragma unroll
    for (int j=0;j<NT;j++){ ghR[j]=b0; ghZ[j]=b1; ghN[j]=b2; }
    #pragma unroll 2
    for (int k4=0;k4<K4;k4++){
      float4 wR = *(const float4*)(wb + k4*WST);
      float4 wZ = *(const float4*)(wb + k4*WST + C*4);
      float4 wN = *(const float4*)(wb + k4*WST + 2*C*4);
      #pragma unroll
      for (int j=0;j<NT;j++){
        float4 a = *(const float4*)(sb + j*C + k4*4);
        ghR[j] = fma4_(ghR[j], a, wR);
        ghZ[j] = fma4_(ghZ[j], a, wZ);
        ghN[j] = fma4_(ghN[j], a, wN);
      }
    }
  }
  // ---- gates ----
  #pragma unroll
  for (int j=0;j<NT;j++){
    int node = base + g*NT + j;
    if (node < n_nodes){
      float h  = stage[(g*NT+j)*C + c];
      float r  = sigmoidf_(giR[j] + ghR[j]);
      float z  = sigmoidf_(giZ[j] + ghZ[j]);
      float nn = tanhf(giN[j] + r*ghN[j]);
      hout[(size_t)node*C + c] = (1.f - z)*nn + z*h;
    }
  }
}

// ---------------- head: elu -> fc1 -> elu -> fc2 -> log_softmax ----------------
__global__ __launch_bounds__(256) void head_kernel(const float* __restrict__ h2,
   const float* __restrict__ fc1w, const float* __restrict__ fc1b,
   const float* __restrict__ fc2w, const float* __restrict__ fc2b,
   float* __restrict__ out, int n){
  __shared__ __align__(16) float W1l[128*64];
  __shared__ float W2l[10*128];
  __shared__ float b1l[128];
  __shared__ float b2l[10];
  int tid = threadIdx.x;
  for (int idx=tid; idx<128*64; idx+=256) W1l[idx]=fc1w[idx];
  for (int idx=tid; idx<10*128; idx+=256) W2l[idx]=fc2w[idx];
  if (tid<128) b1l[tid]=fc1b[tid];
  if (tid<10)  b2l[tid]=fc2b[tid];
  __syncthreads();
  int n0 = blockIdx.x*512 + tid;
  int n1 = n0 + 256;
  bool v0 = n0 < n, v1 = n1 < n;
  float h0[64], h1[64];
  #pragma unroll
  for (int k=0;k<64;k++){
    h0[k] = v0 ? eluf_(h2[(size_t)n0*64+k]) : 0.f;
    h1[k] = v1 ? eluf_(h2[(size_t)n1*64+k]) : 0.f;
  }
  float lg0[10], lg1[10];
  #pragma unroll
  for (int c=0;c<10;c++){ lg0[c]=b2l[c]; lg1[c]=b2l[c]; }
  for (int j=0;j<128;j++){
    float s0 = b1l[j], s1 = b1l[j];
    const float4* w4 = (const float4*)(W1l + j*64);
    #pragma unroll
    for (int q=0;q<16;q++){
      float4 w = w4[q];
      s0 = fmaf(h0[4*q],w.x,fmaf(h0[4*q+1],w.y,fmaf(h0[4*q+2],w.z,fmaf(h0[4*q+3],w.w,s0))));
      s1 = fmaf(h1[4*q],w.x,fmaf(h1[4*q+1],w.y,fmaf(h1[4*q+2],w.z,fmaf(h1[4*q+3],w.w,s1))));
    }
    float e0 = eluf_(s0), e1 = eluf_(s1);
    #pragma unroll
    for (int c=0;c<10;c++){
      float w2 = W2l[c*128+j];
      lg0[c] = fmaf(e0, w2, lg0[c]);
      lg1[c] = fmaf(e1, w2, lg1[c]);
    }
  }
  if (v0){
    float mx = lg0[0];
    #pragma unroll
    for (int c=1;c<10;c++) mx = fmaxf(mx, lg0[c]);
    float s = 0.f;
    #pragma unroll
    for (int c=0;c<10;c++) s += expf(lg0[c]-mx);
    float lse = mx + logf(s);
    #pragma unroll
    for (int c=0;c<10;c++) out[(size_t)n0*10+c] = lg0[c]-lse;
  }
  if (v1){
    float mx = lg1[0];
    #pragma unroll
    for (int c=1;c<10;c++) mx = fmaxf(mx, lg1[c]);
    float s = 0.f;
    #pragma unroll
    for (int c=0;c<10;c++) s += expf(lg1[c]-mx);
    float lse = mx + logf(s);
    #pragma unroll
    for (int c=0;c<10;c++) out[(size_t)n1*10+c] = lg1[c]-lse;
  }
}

extern "C" void kernel_launch(void* const* d_in, const int* in_sizes, int n_in,
                              void* d_out, int out_size, void* d_ws, size_t ws_size,
                              hipStream_t stream){
  const float* x    = (const float*)d_in[0];
  const int*   ei   = (const int*)  d_in[1];
  const float* ea   = (const float*)d_in[2];
  const float* W1   = (const float*)d_in[3];
  const float* Wih1 = (const float*)d_in[4];
  const float* Whh1 = (const float*)d_in[5];
  const float* bih1 = (const float*)d_in[6];
  const float* bhh1 = (const float*)d_in[7];
  const float* W2   = (const float*)d_in[8];
  const float* Wih2 = (const float*)d_in[9];
  const float* Whh2 = (const float*)d_in[10];
  const float* bih2 = (const float*)d_in[11];
  const float* bhh2 = (const float*)d_in[12];
  const float* fc1w = (const float*)d_in[13];
  const float* fc1b = (const float*)d_in[14];
  const float* fc2w = (const float*)d_in[15];
  const float* fc2b = (const float*)d_in[16];
  float* outp = (float*)d_out;

  char* ws = (char*)d_ws;
  size_t off = 0;
  auto alloc = [&](size_t bytes)->void*{
    void* p = ws + off;
    off += (bytes + 255) & ~size_t(255);
    return p;
  };
  float* hA        = (float*)alloc(sizeof(float)*N_NODES*64);
  float* hB        = (float*)alloc(sizeof(float)*N_NODES*64);
  float* mB        = (float*)alloc(sizeof(float)*N_NODES*64);
  float* aggB      = (float*)alloc(sizeof(float)*N_NODES*64);
  int*   row_start = (int*)  alloc(sizeof(int)*(N_NODES+1));
  int*   cnt       = (int*)  alloc(sizeof(int)*N_NODES);
  int*   cur       = (int*)  alloc(sizeof(int)*N_NODES);
  int*   pre       = (int*)  alloc(sizeof(int)*N_NODES);
  int*   bsum      = (int*)  alloc(sizeof(int)*1024);
  int*   ssrc      = (int*)  alloc(sizeof(int)*N_EDGES);
  float* sew       = (float*)alloc(sizeof(float)*N_EDGES);
  (void)ws_size; (void)in_sizes; (void)n_in; (void)out_size;

  const int n = N_NODES, e = N_EDGES;
  const int nb = (n + SCAN_BS - 1)/SCAN_BS;

  zero_counts<<<(n+255)/256,256,0,stream>>>(cnt, cur, n);
  count_kernel<<<(e+255)/256,256,0,stream>>>(ei, cnt, e);
  scan1_kernel<<<nb,SCAN_BS,0,stream>>>(cnt, pre, bsum, n);
  scan2_kernel<<<1,1024,0,stream>>>(bsum, nb);
  scan3_kernel<<<(n+255)/256,256,0,stream>>>(pre, bsum, row_start, n);
  scatter_kernel<<<(e+255)/256,256,0,stream>>>(ei, ea, row_start, cur, ssrc, sew, e);

  // layer 1 (C=32): NB = 8*8 = 64 nodes/block
  pad_x_kernel<<<(n*32+255)/256,256,0,stream>>>(x, hA, n);
  for (int i=0;i<3;i++){
    mgemm_kernel<32,8><<<(n+127)/128,256,0,stream>>>(hA, W1 + i*32*32, mB, n);
    agg_kernel<32><<<((long long)n*32+255)/256,256,0,stream>>>(mB, row_start, ssrc, sew, aggB, n);
    gru_kernel<32,8><<<(n+63)/64,256,0,stream>>>(aggB, hA, Wih1, Whh1, bih1, bhh1, hA, n);
  }

  transition_kernel<<<(n*64+255)/256,256,0,stream>>>(hA, hB, n);

  // layer 2 (C=64): NB = 4*8 = 32 nodes/block
  for (int i=0;i<3;i++){
    mgemm_kernel<64,8><<<(n+63)/64,256,0,stream>>>(hB, W2 + i*64*64, mB, n);
    agg_kernel<64><<<((long long)n*64+255)/256,256,0,stream>>>(mB, row_start, ssrc, sew, aggB, n);
    gru_kernel<64,8><<<(n+31)/32,256,0,stream>>>(aggB, hB, Wih2, Whh2, bih2, bhh2, hB, n);
  }

  head_kernel<<<(n+511)/512,256,0,stream>>>(hB, fc1w, fc1b, fc2w, fc2b, outp, n);
}

// Round 8
// 1235.241 us; speedup vs baseline: 2.5926x; 1.0807x over previous
//
#include <hip/hip_runtime.h>
#include <math.h>

#define N_NODES 100000
#define N_EDGES 1600000
#define SCAN_BS 256

__device__ __forceinline__ float sigmoidf_(float x){ return 1.f/(1.f + expf(-x)); }
__device__ __forceinline__ float eluf_(float x){ return x > 0.f ? x : expm1f(x); }

__device__ __forceinline__ float fma4_(float acc, float4 a, float4 b){
  return fmaf(a.x,b.x, fmaf(a.y,b.y, fmaf(a.z,b.z, fmaf(a.w,b.w,acc))));
}

// ---------------- CSR build (dst-sorted edge lists) ----------------
__global__ void zero_counts(int* cnt, int* cur, int n){
  int i = blockIdx.x*blockDim.x + threadIdx.x;
  if (i < n){ cnt[i]=0; cur[i]=0; }
}
__global__ void count_kernel(const int* __restrict__ ei, int* __restrict__ cnt, int e){
  int i = blockIdx.x*blockDim.x + threadIdx.x;
  if (i < e) atomicAdd(&cnt[ei[N_EDGES + i]], 1);
}
__global__ void scan1_kernel(const int* __restrict__ cnt, int* __restrict__ pre,
                             int* __restrict__ bsum, int n){
  __shared__ int sh[SCAN_BS];
  int t = threadIdx.x, gi = blockIdx.x*SCAN_BS + t;
  int v = (gi < n) ? cnt[gi] : 0;
  sh[t] = v;
  __syncthreads();
  for (int off=1; off<SCAN_BS; off<<=1){
    int u = (t>=off)?sh[t-off]:0;
    __syncthreads();
    sh[t] += u;
    __syncthreads();
  }
  if (gi < n) pre[gi] = sh[t] - v;
  if (t == SCAN_BS-1) bsum[blockIdx.x] = sh[t];
}
__global__ void scan2_kernel(int* __restrict__ bsum, int nb){
  __shared__ int sh[1024];
  int t = threadIdx.x;
  int v = (t < nb) ? bsum[t] : 0;
  sh[t] = v;
  __syncthreads();
  for (int off=1; off<1024; off<<=1){
    int u = (t>=off)?sh[t-off]:0;
    __syncthreads();
    sh[t] += u;
    __syncthreads();
  }
  if (t < nb) bsum[t] = sh[t] - v;
}
__global__ void scan3_kernel(const int* __restrict__ pre, const int* __restrict__ bsum,
                             int* __restrict__ row_start, int n){
  int i = blockIdx.x*blockDim.x + threadIdx.x;
  if (i < n) row_start[i] = pre[i] + bsum[i/SCAN_BS];
  if (i == 0) row_start[n] = N_EDGES;
}
// one 8B write per edge: {src, ew_bits} (halves scattered-line touches vs 2x4B)
__global__ void scatter_kernel(const int* __restrict__ ei, const float* __restrict__ ea,
    const int* __restrict__ row_start, int* __restrict__ cur,
    int2* __restrict__ esrc, int e){
  int i = blockIdx.x*blockDim.x + threadIdx.x;
  if (i < e){
    int d = ei[N_EDGES + i];
    int p = row_start[d] + atomicAdd(&cur[d], 1);
    esrc[p] = make_int2(ei[i], __float_as_int(ea[i]));
  }
}

// ---------------- elementwise ----------------
__global__ void pad_x_kernel(const float* __restrict__ x, float* __restrict__ h, int n){
  int i = blockIdx.x*blockDim.x + threadIdx.x;
  if (i < n*32){
    int node = i >> 5, c = i & 31;
    h[i] = (c < 16) ? x[node*16 + c] : 0.f;
  }
}
__global__ void transition_kernel(const float* __restrict__ h1, float* __restrict__ h2, int n){
  int i = blockIdx.x*blockDim.x + threadIdx.x;
  if (i < n*64){
    int node = i >> 6, c = i & 63;
    h2[i] = (c < 32) ? eluf_(h1[node*32 + c]) : 0.f;
  }
}

// ---------------- m = h @ W  (C x C): k4-blocked, b128 LDS reads ----------------
template<int C, int NT>
__global__ __launch_bounds__(256) void mgemm_kernel(const float* __restrict__ hin,
    const float* __restrict__ W, float* __restrict__ mout, int n){
  constexpr int HC = C/2;
  constexpr int G = 256/HC;
  constexpr int NB = G*NT;
  constexpr int K4 = C/4;
  constexpr int WST = C*4 + 4;           // dwords per k4 block (pad -> write 2-way only)
  __shared__ __align__(16) float Wl4[K4*WST];
  __shared__ __align__(16) float stage[NB*C];
  int tid = threadIdx.x;
  int cc = tid % HC, g = tid / HC;
  int base = blockIdx.x * NB;
  // weights: W[k*C+c] -> Wl4[(k>>2)*WST + c*4 + (k&3)]
  for (int idx=tid; idx<C*C; idx+=256){
    int k = idx / C, c = idx % C;
    Wl4[(k>>2)*WST + c*4 + (k&3)] = W[idx];
  }
  // stage fill: vectorized b128
  for (int i4=tid; i4<NB*C/4; i4+=256){
    int node = base + (i4*4)/C;
    ((float4*)stage)[i4] = (node < n) ? *((const float4*)(hin + (size_t)node*C + (i4*4)%C))
                                      : float4{0.f,0.f,0.f,0.f};
  }
  __syncthreads();
  float acc0[NT], acc1[NT];
  #pragma unroll
  for(int j=0;j<NT;j++){acc0[j]=0.f;acc1[j]=0.f;}
  const float* wb = Wl4 + cc*4;
  const float* sb = stage + g*NT*C;
  #pragma unroll 2
  for (int k4=0;k4<K4;k4++){
    float4 w0 = *(const float4*)(wb + k4*WST);
    float4 w1 = *(const float4*)(wb + k4*WST + HC*4);
    #pragma unroll
    for (int j=0;j<NT;j++){
      float4 a = *(const float4*)(sb + j*C + k4*4);
      acc0[j] = fma4_(acc0[j], a, w0);
      acc1[j] = fma4_(acc1[j], a, w1);
    }
  }
  #pragma unroll
  for (int j=0;j<NT;j++){
    int node = base + g*NT + j;
    if (node < n){
      mout[(size_t)node*C + cc]      = acc0[j];
      mout[(size_t)node*C + cc + HC] = acc1[j];
    }
  }
}

// ---------------- agg[n][c] = max over incoming edges of m[src][c]*ew, else 0 ----------------
template<int C>
__global__ void agg_kernel(const float* __restrict__ m, const int* __restrict__ row_start,
    const int2* __restrict__ esrc, float* __restrict__ agg, int n_nodes){
  int gid = blockIdx.x*blockDim.x + threadIdx.x;
  int nn = gid / C, c = gid % C;
  if (nn >= n_nodes) return;
  int s = row_start[nn], e = row_start[nn+1];
  float acc = -__builtin_inff();
  int i = s;
  for (; i+2<=e; i+=2){                  // 2 independent m-loads in flight
    int2 e0 = esrc[i], e1 = esrc[i+1];
    float v0 = m[(size_t)e0.x*C + c]*__int_as_float(e0.y);
    float v1 = m[(size_t)e1.x*C + c]*__int_as_float(e1.y);
    acc = fmaxf(acc, fmaxf(v0, v1));
  }
  if (i < e){
    int2 e0 = esrc[i];
    acc = fmaxf(acc, m[(size_t)e0.x*C + c]*__int_as_float(e0.y));
  }
  agg[(size_t)nn*C+c] = (e > s) ? acc : 0.f;
}

// ---------------- fused GRU cell: k4-blocked weights, b128 LDS reads ----------
// K4 loop capped at unroll 2 (R6 lesson: full unroll -> 256 VGPR + 765MB spill).
template<int C, int NT>
__global__ __launch_bounds__(256) void gru_kernel(
    const float* __restrict__ agg, const float* __restrict__ hin,
    const float* __restrict__ Wih, const float* __restrict__ Whh,
    const float* __restrict__ bih, const float* __restrict__ bhh,
    float* __restrict__ hout, int n_nodes){
  constexpr int G  = 256 / C;
  constexpr int NB = G * NT;
  constexpr int R  = 3 * C;
  constexpr int K4 = C/4;
  constexpr int WST = R*4 + 4;
  __shared__ __align__(16) float WT4[K4*WST];
  __shared__ __align__(16) float stage[NB*C];
  int tid = threadIdx.x;
  int c = tid % C;
  int g = tid / C;
  int base = blockIdx.x * NB;

  float giR[NT], giZ[NT], giN[NT];
  float ghR[NT], ghZ[NT], ghN[NT];

  const float* wb = WT4 + c*4;
  const float* sb = stage + g*NT*C;

  // ---- phase 1: gi = agg @ Wih^T + bih ----
  for (int i4=tid; i4<C*R/4; i4+=256){
    float4 v = ((const float4*)Wih)[i4];
    int idx = i4*4;
    int r = idx / C, k = idx % C;              // k multiple of 4
    *(float4*)(WT4 + (k>>2)*WST + r*4) = v;
  }
  for (int i4=tid; i4<NB*C/4; i4+=256){
    int node = base + (i4*4)/C;
    ((float4*)stage)[i4] = (node < n_nodes) ? *((const float4*)(agg + (size_t)node*C + (i4*4)%C))
                                            : float4{0.f,0.f,0.f,0.f};
  }
  __syncthreads();
  {
    float b0 = bih[c], b1 = bih[c+C], b2 = bih[c+2*C];
    #pragma unroll
    for (int j=0;j<NT;j++){ giR[j]=b0; giZ[j]=b1; giN[j]=b2; }
    #pragma unroll 2
    for (int k4=0;k4<K4;k4++){
      float4 wR = *(const float4*)(wb + k4*WST);
      float4 wZ = *(const float4*)(wb + k4*WST + C*4);
      float4 wN = *(const float4*)(wb + k4*WST + 2*C*4);
      #pragma unroll
      for (int j=0;j<NT;j++){
        float4 a = *(const float4*)(sb + j*C + k4*4);
        giR[j] = fma4_(giR[j], a, wR);
        giZ[j] = fma4_(giZ[j], a, wZ);
        giN[j] = fma4_(giN[j], a, wN);
      }
    }
  }
  __syncthreads();
  // ---- phase 2: gh = h @ Whh^T + bhh ----
  for (int i4=tid; i4<C*R/4; i4+=256){
    float4 v = ((const float4*)Whh)[i4];
    int idx = i4*4;
    int r = idx / C, k = idx % C;
    *(float4*)(WT4 + (k>>2)*WST + r*4) = v;
  }
  for (int i4=tid; i4<NB*C/4; i4+=256){
    int node = base + (i4*4)/C;
    ((float4*)stage)[i4] = (node < n_nodes) ? *((const float4*)(hin + (size_t)node*C + (i4*4)%C))
                                            : float4{0.f,0.f,0.f,0.f};
  }
  __syncthreads();
  {
    float b0 = bhh[c], b1 = bhh[c+C], b2 = bhh[c+2*C];
    #pragma unroll
    for (int j=0;j<NT;j++){ ghR[j]=b0; ghZ[j]=b1; ghN[j]=b2; }
    #pragma unroll 2
    for (int k4=0;k4<K4;k4++){
      float4 wR = *(const float4*)(wb + k4*WST);
      float4 wZ = *(const float4*)(wb + k4*WST + C*4);
      float4 wN = *(const float4*)(wb + k4*WST + 2*C*4);
      #pragma unroll
      for (int j=0;j<NT;j++){
        float4 a = *(const float4*)(sb + j*C + k4*4);
        ghR[j] = fma4_(ghR[j], a, wR);
        ghZ[j] = fma4_(ghZ[j], a, wZ);
        ghN[j] = fma4_(ghN[j], a, wN);
      }
    }
  }
  // ---- gates ----
  #pragma unroll
  for (int j=0;j<NT;j++){
    int node = base + g*NT + j;
    if (node < n_nodes){
      float h  = stage[(g*NT+j)*C + c];
      float r  = sigmoidf_(giR[j] + ghR[j]);
      float z  = sigmoidf_(giZ[j] + ghZ[j]);
      float nn = tanhf(giN[j] + r*ghN[j]);
      hout[(size_t)node*C + c] = (1.f - z)*nn + z*h;
    }
  }
}

// ---------------- head: elu -> fc1 -> elu -> fc2 -> log_softmax ----------------
__global__ __launch_bounds__(256) void head_kernel(const float* __restrict__ h2,
   const float* __restrict__ fc1w, const float* __restrict__ fc1b,
   const float* __restrict__ fc2w, const float* __restrict__ fc2b,
   float* __restrict__ out, int n){
  __shared__ __align__(16) float W1l[128*64];
  __shared__ float W2l[10*128];
  __shared__ float b1l[128];
  __shared__ float b2l[10];
  int tid = threadIdx.x;
  for (int idx=tid; idx<128*64; idx+=256) W1l[idx]=fc1w[idx];
  for (int idx=tid; idx<10*128; idx+=256) W2l[idx]=fc2w[idx];
  if (tid<128) b1l[tid]=fc1b[tid];
  if (tid<10)  b2l[tid]=fc2b[tid];
  __syncthreads();
  int n0 = blockIdx.x*512 + tid;
  int n1 = n0 + 256;
  bool v0 = n0 < n, v1 = n1 < n;
  float h0[64], h1[64];
  #pragma unroll
  for (int k=0;k<64;k++){
    h0[k] = v0 ? eluf_(h2[(size_t)n0*64+k]) : 0.f;
    h1[k] = v1 ? eluf_(h2[(size_t)n1*64+k]) : 0.f;
  }
  float lg0[10], lg1[10];
  #pragma unroll
  for (int c=0;c<10;c++){ lg0[c]=b2l[c]; lg1[c]=b2l[c]; }
  for (int j=0;j<128;j++){
    float s0 = b1l[j], s1 = b1l[j];
    const float4* w4 = (const float4*)(W1l + j*64);
    #pragma unroll
    for (int q=0;q<16;q++){
      float4 w = w4[q];
      s0 = fmaf(h0[4*q],w.x,fmaf(h0[4*q+1],w.y,fmaf(h0[4*q+2],w.z,fmaf(h0[4*q+3],w.w,s0))));
      s1 = fmaf(h1[4*q],w.x,fmaf(h1[4*q+1],w.y,fmaf(h1[4*q+2],w.z,fmaf(h1[4*q+3],w.w,s1))));
    }
    float e0 = eluf_(s0), e1 = eluf_(s1);
    #pragma unroll
    for (int c=0;c<10;c++){
      float w2 = W2l[c*128+j];
      lg0[c] = fmaf(e0, w2, lg0[c]);
      lg1[c] = fmaf(e1, w2, lg1[c]);
    }
  }
  if (v0){
    float mx = lg0[0];
    #pragma unroll
    for (int c=1;c<10;c++) mx = fmaxf(mx, lg0[c]);
    float s = 0.f;
    #pragma unroll
    for (int c=0;c<10;c++) s += expf(lg0[c]-mx);
    float lse = mx + logf(s);
    #pragma unroll
    for (int c=0;c<10;c++) out[(size_t)n0*10+c] = lg0[c]-lse;
  }
  if (v1){
    float mx = lg1[0];
    #pragma unroll
    for (int c=1;c<10;c++) mx = fmaxf(mx, lg1[c]);
    float s = 0.f;
    #pragma unroll
    for (int c=0;c<10;c++) s += expf(lg1[c]-mx);
    float lse = mx + logf(s);
    #pragma unroll
    for (int c=0;c<10;c++) out[(size_t)n1*10+c] = lg1[c]-lse;
  }
}

extern "C" void kernel_launch(void* const* d_in, const int* in_sizes, int n_in,
                              void* d_out, int out_size, void* d_ws, size_t ws_size,
                              hipStream_t stream){
  const float* x    = (const float*)d_in[0];
  const int*   ei   = (const int*)  d_in[1];
  const float* ea   = (const float*)d_in[2];
  const float* W1   = (const float*)d_in[3];
  const float* Wih1 = (const float*)d_in[4];
  const float* Whh1 = (const float*)d_in[5];
  const float* bih1 = (const float*)d_in[6];
  const float* bhh1 = (const float*)d_in[7];
  const float* W2   = (const float*)d_in[8];
  const float* Wih2 = (const float*)d_in[9];
  const float* Whh2 = (const float*)d_in[10];
  const float* bih2 = (const float*)d_in[11];
  const float* bhh2 = (const float*)d_in[12];
  const float* fc1w = (const float*)d_in[13];
  const float* fc1b = (const float*)d_in[14];
  const float* fc2w = (const float*)d_in[15];
  const float* fc2b = (const float*)d_in[16];
  float* outp = (float*)d_out;

  char* ws = (char*)d_ws;
  size_t off = 0;
  auto alloc = [&](size_t bytes)->void*{
    void* p = ws + off;
    off += (bytes + 255) & ~size_t(255);
    return p;
  };
  float* hA        = (float*)alloc(sizeof(float)*N_NODES*64);
  float* hB        = (float*)alloc(sizeof(float)*N_NODES*64);
  float* mB        = (float*)alloc(sizeof(float)*N_NODES*64);
  float* aggB      = (float*)alloc(sizeof(float)*N_NODES*64);
  int*   row_start = (int*)  alloc(sizeof(int)*(N_NODES+1));
  int*   cnt       = (int*)  alloc(sizeof(int)*N_NODES);
  int*   cur       = (int*)  alloc(sizeof(int)*N_NODES);
  int*   pre       = (int*)  alloc(sizeof(int)*N_NODES);
  int*   bsum      = (int*)  alloc(sizeof(int)*1024);
  int2*  esrc      = (int2*) alloc(sizeof(int2)*N_EDGES);
  (void)ws_size; (void)in_sizes; (void)n_in; (void)out_size;

  const int n = N_NODES, e = N_EDGES;
  const int nb = (n + SCAN_BS - 1)/SCAN_BS;

  zero_counts<<<(n+255)/256,256,0,stream>>>(cnt, cur, n);
  count_kernel<<<(e+255)/256,256,0,stream>>>(ei, cnt, e);
  scan1_kernel<<<nb,SCAN_BS,0,stream>>>(cnt, pre, bsum, n);
  scan2_kernel<<<1,1024,0,stream>>>(bsum, nb);
  scan3_kernel<<<(n+255)/256,256,0,stream>>>(pre, bsum, row_start, n);
  scatter_kernel<<<(e+255)/256,256,0,stream>>>(ei, ea, row_start, cur, esrc, e);

  // layer 1 (C=32): mgemm NB=256, gru NB=128
  pad_x_kernel<<<(n*32+255)/256,256,0,stream>>>(x, hA, n);
  for (int i=0;i<3;i++){
    mgemm_kernel<32,16><<<(n+255)/256,256,0,stream>>>(hA, W1 + i*32*32, mB, n);
    agg_kernel<32><<<((long long)n*32+255)/256,256,0,stream>>>(mB, row_start, esrc, aggB, n);
    gru_kernel<32,16><<<(n+127)/128,256,0,stream>>>(aggB, hA, Wih1, Whh1, bih1, bhh1, hA, n);
  }

  transition_kernel<<<(n*64+255)/256,256,0,stream>>>(hA, hB, n);

  // layer 2 (C=64): mgemm NB=128, gru NB=64
  for (int i=0;i<3;i++){
    mgemm_kernel<64,16><<<(n+127)/128,256,0,stream>>>(hB, W2 + i*64*64, mB, n);
    agg_kernel<64><<<((long long)n*64+255)/256,256,0,stream>>>(mB, row_start, esrc, aggB, n);
    gru_kernel<64,16><<<(n+63)/64,256,0,stream>>>(aggB, hB, Wih2, Whh2, bih2, bhh2, hB, n);
  }

  head_kernel<<<(n+511)/512,256,0,stream>>>(hB, fc1w, fc1b, fc2w, fc2b, outp, n);
}

// Round 9
// 914.288 us; speedup vs baseline: 3.5027x; 1.3510x over previous
//
#include <hip/hip_runtime.h>
#include <math.h>

#define N_NODES 100000
#define N_EDGES 1600000
#define SCAN_BS 256

typedef __attribute__((ext_vector_type(8))) short bf8_t;   // 8 bf16 in 4 VGPRs
typedef __attribute__((ext_vector_type(4))) float f4_t;

__device__ __forceinline__ float sigmoidf_(float x){ return 1.f/(1.f + expf(-x)); }
__device__ __forceinline__ float eluf_(float x){ return x > 0.f ? x : expm1f(x); }
__device__ __forceinline__ unsigned short f2bf(float x){
  unsigned u = __float_as_uint(x);
  unsigned r = u + 0x7FFFu + ((u>>16)&1u);
  return (unsigned short)(r>>16);
}
__device__ __forceinline__ float bf2f(unsigned short v){
  return __uint_as_float(((unsigned)v)<<16);
}

// ---------------- weight prep ----------------
__global__ void conv_bf16_kernel(const float* __restrict__ s, unsigned short* __restrict__ d, int n){
  int i = blockIdx.x*256 + threadIdx.x;
  if (i < n) d[i] = f2bf(s[i]);
}
// d[m][c][k] = s[m][k][c]  (out-major transposed, bf16)
__global__ void convT_bf16_kernel(const float* __restrict__ s, unsigned short* __restrict__ d, int C, int total){
  int i = blockIdx.x*256 + threadIdx.x;
  if (i < total){
    int k = i % C; int c = (i/C)%C; int m = i/(C*C);
    d[i] = f2bf(s[(size_t)m*C*C + (size_t)k*C + c]);
  }
}

// ---------------- CSR build ----------------
__global__ void zero_counts(int* cnt, int* cur, int n){
  int i = blockIdx.x*blockDim.x + threadIdx.x;
  if (i < n){ cnt[i]=0; cur[i]=0; }
}
__global__ void count_kernel(const int* __restrict__ ei, int* __restrict__ cnt, int e){
  int i = blockIdx.x*blockDim.x + threadIdx.x;
  if (i < e) atomicAdd(&cnt[ei[N_EDGES + i]], 1);
}
__global__ void scan1_kernel(const int* __restrict__ cnt, int* __restrict__ pre,
                             int* __restrict__ bsum, int n){
  __shared__ int sh[SCAN_BS];
  int t = threadIdx.x, gi = blockIdx.x*SCAN_BS + t;
  int v = (gi < n) ? cnt[gi] : 0;
  sh[t] = v;
  __syncthreads();
  for (int off=1; off<SCAN_BS; off<<=1){
    int u = (t>=off)?sh[t-off]:0;
    __syncthreads();
    sh[t] += u;
    __syncthreads();
  }
  if (gi < n) pre[gi] = sh[t] - v;
  if (t == SCAN_BS-1) bsum[blockIdx.x] = sh[t];
}
__global__ void scan2_kernel(int* __restrict__ bsum, int nb){
  __shared__ int sh[1024];
  int t = threadIdx.x;
  int v = (t < nb) ? bsum[t] : 0;
  sh[t] = v;
  __syncthreads();
  for (int off=1; off<1024; off<<=1){
    int u = (t>=off)?sh[t-off]:0;
    __syncthreads();
    sh[t] += u;
    __syncthreads();
  }
  if (t < nb) bsum[t] = sh[t] - v;
}
__global__ void scan3_kernel(const int* __restrict__ pre, const int* __restrict__ bsum,
                             int* __restrict__ row_start, int n){
  int i = blockIdx.x*blockDim.x + threadIdx.x;
  if (i < n) row_start[i] = pre[i] + bsum[i/SCAN_BS];
  if (i == 0) row_start[n] = N_EDGES;
}
__global__ void scatter_kernel(const int* __restrict__ ei, const float* __restrict__ ea,
    const int* __restrict__ row_start, int* __restrict__ cur,
    int2* __restrict__ esrc, int e){
  int i = blockIdx.x*blockDim.x + threadIdx.x;
  if (i < e){
    int d = ei[N_EDGES + i];
    int p = row_start[d] + atomicAdd(&cur[d], 1);
    esrc[p] = make_int2(ei[i], __float_as_int(ea[i]));
  }
}

// ---------------- elementwise ----------------
__global__ void pad_x_kernel(const float* __restrict__ x, float* __restrict__ h,
                             unsigned short* __restrict__ hb, int n){
  int i = blockIdx.x*blockDim.x + threadIdx.x;
  if (i < n*32){
    int node = i >> 5, c = i & 31;
    float v = (c < 16) ? x[node*16 + c] : 0.f;
    h[i] = v;
    hb[i] = f2bf(v);
  }
}
__global__ void transition_kernel(const float* __restrict__ h1, float* __restrict__ h2,
                                  unsigned short* __restrict__ h2b, int n){
  int i = blockIdx.x*blockDim.x + threadIdx.x;
  if (i < n*64){
    int node = i >> 6, c = i & 63;
    float v = (c < 32) ? eluf_(h1[node*32 + c]) : 0.f;
    h2[i] = v;
    h2b[i] = f2bf(v);
  }
}

// ---------------- m = h @ W via MFMA: one wave = 16 nodes ----------------
// A-frag: lane l holds A[row=l&15][k = 8*(l>>4)+j]  (16B contiguous from row-major bf16)
// B-frag: lane l holds B[k][col=l&15] = Wt[col][k]  (Wt = W^T, out-major)
// D: lane l holds D[row=(l>>4)*4+r][col=l&15]
template<int C>
__global__ __launch_bounds__(256) void mgemm_mfma(const unsigned short* __restrict__ hb,
    const unsigned short* __restrict__ Wtb, unsigned short* __restrict__ mb, int n){
  constexpr int NT = C/16, KS = C/32;
  int l = threadIdx.x & 63, w = threadIdx.x >> 6;
  int mbase = blockIdx.x*64 + w*16;
  if (mbase >= n) return;
  int lr = l & 15, lk = (l >> 4)*8;
  f4_t acc[NT];
  #pragma unroll
  for (int t=0;t<NT;t++) acc[t] = f4_t{0.f,0.f,0.f,0.f};
  #pragma unroll
  for (int ks=0; ks<KS; ks++){
    int k0 = ks*32 + lk;
    bf8_t a = *(const bf8_t*)(hb + (size_t)(mbase+lr)*C + k0);
    #pragma unroll
    for (int t=0;t<NT;t++){
      bf8_t b = *(const bf8_t*)(Wtb + (size_t)(t*16+lr)*C + k0);
      acc[t] = __builtin_amdgcn_mfma_f32_16x16x32_bf16(a, b, acc[t], 0, 0, 0);
    }
  }
  int dr = (l>>4)*4;
  #pragma unroll
  for (int t=0;t<NT;t++){
    #pragma unroll
    for (int r=0;r<4;r++)
      mb[(size_t)(mbase+dr+r)*C + t*16 + lr] = f2bf(acc[t][r]);
  }
}

// ---------------- agg (bf16 in/out) ----------------
template<int C>
__global__ void agg_kernel(const unsigned short* __restrict__ mb, const int* __restrict__ row_start,
    const int2* __restrict__ esrc, unsigned short* __restrict__ aggb, int n_nodes){
  int gid = blockIdx.x*blockDim.x + threadIdx.x;
  int nn = gid / C, c = gid % C;
  if (nn >= n_nodes) return;
  int s = row_start[nn], e = row_start[nn+1];
  float acc = -__builtin_inff();
  int i = s;
  for (; i+2<=e; i+=2){
    int2 e0 = esrc[i], e1 = esrc[i+1];
    float v0 = bf2f(mb[(size_t)e0.x*C + c])*__int_as_float(e0.y);
    float v1 = bf2f(mb[(size_t)e1.x*C + c])*__int_as_float(e1.y);
    acc = fmaxf(acc, fmaxf(v0, v1));
  }
  if (i < e){
    int2 e0 = esrc[i];
    acc = fmaxf(acc, bf2f(mb[(size_t)e0.x*C + c])*__int_as_float(e0.y));
  }
  aggb[(size_t)nn*C+c] = (e > s) ? f2bf(acc) : (unsigned short)0;
}

// ---------------- fused GRU via MFMA ----------------
// gi = aggb @ Wihb^T, gh = hbin @ Whhb^T   (Wihb/Whhb row-major [3C][C] bf16 = B-frag-ready)
// then gates in fp32; writes h fp32 (in-place safe) + bf16 (double-buffered).
template<int C>
__global__ __launch_bounds__(256) void gru_mfma(
    const unsigned short* __restrict__ aggb, const unsigned short* __restrict__ hbin,
    const float* __restrict__ hfin,
    const unsigned short* __restrict__ Wihb, const unsigned short* __restrict__ Whhb,
    const float* __restrict__ bih, const float* __restrict__ bhh,
    float* __restrict__ hfout, unsigned short* __restrict__ hbout, int n){
  constexpr int NT = 3*C/16;    // 12 for C=64, 6 for C=32
  constexpr int KS = C/32;      // 2 / 1
  constexpr int CT = C/16;      // 4 / 2
  int l = threadIdx.x & 63, w = threadIdx.x >> 6;
  int mbase = blockIdx.x*64 + w*16;
  if (mbase >= n) return;
  int lr = l & 15, lk = (l >> 4)*8;
  f4_t accI[NT], accH[NT];
  #pragma unroll
  for (int t=0;t<NT;t++){ accI[t]=f4_t{0.f,0.f,0.f,0.f}; accH[t]=f4_t{0.f,0.f,0.f,0.f}; }
  #pragma unroll
  for (int ks=0; ks<KS; ks++){
    int k0 = ks*32 + lk;
    bf8_t aI = *(const bf8_t*)(aggb + (size_t)(mbase+lr)*C + k0);
    bf8_t aH = *(const bf8_t*)(hbin + (size_t)(mbase+lr)*C + k0);
    #pragma unroll
    for (int t=0;t<NT;t++){
      bf8_t bI = *(const bf8_t*)(Wihb + (size_t)(t*16+lr)*C + k0);
      accI[t] = __builtin_amdgcn_mfma_f32_16x16x32_bf16(aI, bI, accI[t], 0, 0, 0);
      bf8_t bH = *(const bf8_t*)(Whhb + (size_t)(t*16+lr)*C + k0);
      accH[t] = __builtin_amdgcn_mfma_f32_16x16x32_bf16(aH, bH, accH[t], 0, 0, 0);
    }
  }
  int dr = (l>>4)*4;
  #pragma unroll
  for (int ct=0; ct<CT; ct++){
    int c = ct*16 + lr;
    float bR = bih[c],     cR = bhh[c];
    float bZ = bih[c+C],   cZ = bhh[c+C];
    float bN = bih[c+2*C], cN = bhh[c+2*C];
    #pragma unroll
    for (int r=0;r<4;r++){
      int i = mbase + dr + r;
      float giR = accI[ct][r] + bR,      ghR = accH[ct][r] + cR;
      float giZ = accI[CT+ct][r] + bZ,   ghZ = accH[CT+ct][r] + cZ;
      float giN = accI[2*CT+ct][r] + bN, ghN = accH[2*CT+ct][r] + cN;
      float rr = sigmoidf_(giR + ghR);
      float z  = sigmoidf_(giZ + ghZ);
      float nn = tanhf(giN + rr*ghN);
      float h  = hfin[(size_t)i*C + c];
      float ho = (1.f - z)*nn + z*h;
      hfout[(size_t)i*C + c] = ho;
      hbout[(size_t)i*C + c] = f2bf(ho);
    }
  }
}

// ---------------- head: elu -> fc1 -> elu -> fc2 -> log_softmax (fp32) ----------------
__global__ __launch_bounds__(256) void head_kernel(const float* __restrict__ h2,
   const float* __restrict__ fc1w, const float* __restrict__ fc1b,
   const float* __restrict__ fc2w, const float* __restrict__ fc2b,
   float* __restrict__ out, int n){
  __shared__ __align__(16) float W1l[128*64];
  __shared__ float W2l[10*128];
  __shared__ float b1l[128];
  __shared__ float b2l[10];
  int tid = threadIdx.x;
  for (int idx=tid; idx<128*64; idx+=256) W1l[idx]=fc1w[idx];
  for (int idx=tid; idx<10*128; idx+=256) W2l[idx]=fc2w[idx];
  if (tid<128) b1l[tid]=fc1b[tid];
  if (tid<10)  b2l[tid]=fc2b[tid];
  __syncthreads();
  int n0 = blockIdx.x*512 + tid;
  int n1 = n0 + 256;
  bool v0 = n0 < n, v1 = n1 < n;
  float h0[64], h1[64];
  #pragma unroll
  for (int k=0;k<64;k++){
    h0[k] = v0 ? eluf_(h2[(size_t)n0*64+k]) : 0.f;
    h1[k] = v1 ? eluf_(h2[(size_t)n1*64+k]) : 0.f;
  }
  float lg0[10], lg1[10];
  #pragma unroll
  for (int c=0;c<10;c++){ lg0[c]=b2l[c]; lg1[c]=b2l[c]; }
  for (int j=0;j<128;j++){
    float s0 = b1l[j], s1 = b1l[j];
    const float4* w4 = (const float4*)(W1l + j*64);
    #pragma unroll
    for (int q=0;q<16;q++){
      float4 w = w4[q];
      s0 = fmaf(h0[4*q],w.x,fmaf(h0[4*q+1],w.y,fmaf(h0[4*q+2],w.z,fmaf(h0[4*q+3],w.w,s0))));
      s1 = fmaf(h1[4*q],w.x,fmaf(h1[4*q+1],w.y,fmaf(h1[4*q+2],w.z,fmaf(h1[4*q+3],w.w,s1))));
    }
    float e0 = eluf_(s0), e1 = eluf_(s1);
    #pragma unroll
    for (int c=0;c<10;c++){
      float w2 = W2l[c*128+j];
      lg0[c] = fmaf(e0, w2, lg0[c]);
      lg1[c] = fmaf(e1, w2, lg1[c]);
    }
  }
  if (v0){
    float mx = lg0[0];
    #pragma unroll
    for (int c=1;c<10;c++) mx = fmaxf(mx, lg0[c]);
    float s = 0.f;
    #pragma unroll
    for (int c=0;c<10;c++) s += expf(lg0[c]-mx);
    float lse = mx + logf(s);
    #pragma unroll
    for (int c=0;c<10;c++) out[(size_t)n0*10+c] = lg0[c]-lse;
  }
  if (v1){
    float mx = lg1[0];
    #pragma unroll
    for (int c=1;c<10;c++) mx = fmaxf(mx, lg1[c]);
    float s = 0.f;
    #pragma unroll
    for (int c=0;c<10;c++) s += expf(lg1[c]-mx);
    float lse = mx + logf(s);
    #pragma unroll
    for (int c=0;c<10;c++) out[(size_t)n1*10+c] = lg1[c]-lse;
  }
}

extern "C" void kernel_launch(void* const* d_in, const int* in_sizes, int n_in,
                              void* d_out, int out_size, void* d_ws, size_t ws_size,
                              hipStream_t stream){
  const float* x    = (const float*)d_in[0];
  const int*   ei   = (const int*)  d_in[1];
  const float* ea   = (const float*)d_in[2];
  const float* W1   = (const float*)d_in[3];
  const float* Wih1 = (const float*)d_in[4];
  const float* Whh1 = (const float*)d_in[5];
  const float* bih1 = (const float*)d_in[6];
  const float* bhh1 = (const float*)d_in[7];
  const float* W2   = (const float*)d_in[8];
  const float* Wih2 = (const float*)d_in[9];
  const float* Whh2 = (const float*)d_in[10];
  const float* bih2 = (const float*)d_in[11];
  const float* bhh2 = (const float*)d_in[12];
  const float* fc1w = (const float*)d_in[13];
  const float* fc1b = (const float*)d_in[14];
  const float* fc2w = (const float*)d_in[15];
  const float* fc2b = (const float*)d_in[16];
  float* outp = (float*)d_out;

  char* ws = (char*)d_ws;
  size_t off = 0;
  auto alloc = [&](size_t bytes)->void*{
    void* p = ws + off;
    off += (bytes + 255) & ~size_t(255);
    return p;
  };
  typedef unsigned short us;
  float* hA   = (float*)alloc(sizeof(float)*N_NODES*32);
  float* hB   = (float*)alloc(sizeof(float)*N_NODES*64);
  us* hAb0    = (us*)alloc(sizeof(us)*N_NODES*32);
  us* hAb1    = (us*)alloc(sizeof(us)*N_NODES*32);
  us* hBb0    = (us*)alloc(sizeof(us)*N_NODES*64);
  us* hBb1    = (us*)alloc(sizeof(us)*N_NODES*64);
  us* mb      = (us*)alloc(sizeof(us)*N_NODES*64);
  us* aggb    = (us*)alloc(sizeof(us)*N_NODES*64);
  int* row_start = (int*)alloc(sizeof(int)*(N_NODES+1));
  int* cnt    = (int*)alloc(sizeof(int)*N_NODES);
  int* cur    = (int*)alloc(sizeof(int)*N_NODES);
  int* pre    = (int*)alloc(sizeof(int)*N_NODES);
  int* bsum   = (int*)alloc(sizeof(int)*1024);
  int2* esrc  = (int2*)alloc(sizeof(int2)*N_EDGES);
  us* Wihb1   = (us*)alloc(sizeof(us)*96*32);
  us* Whhb1   = (us*)alloc(sizeof(us)*96*32);
  us* Wihb2   = (us*)alloc(sizeof(us)*192*64);
  us* Whhb2   = (us*)alloc(sizeof(us)*192*64);
  us* Wtb1    = (us*)alloc(sizeof(us)*3*32*32);
  us* Wtb2    = (us*)alloc(sizeof(us)*3*64*64);
  (void)ws_size; (void)in_sizes; (void)n_in; (void)out_size;

  const int n = N_NODES, e = N_EDGES;
  const int nb = (n + SCAN_BS - 1)/SCAN_BS;
  const int gblk = (n + 63)/64;             // 1563

  // weight prep (bf16)
  conv_bf16_kernel<<<(96*32+255)/256,256,0,stream>>>(Wih1, Wihb1, 96*32);
  conv_bf16_kernel<<<(96*32+255)/256,256,0,stream>>>(Whh1, Whhb1, 96*32);
  conv_bf16_kernel<<<(192*64+255)/256,256,0,stream>>>(Wih2, Wihb2, 192*64);
  conv_bf16_kernel<<<(192*64+255)/256,256,0,stream>>>(Whh2, Whhb2, 192*64);
  convT_bf16_kernel<<<(3*32*32+255)/256,256,0,stream>>>(W1, Wtb1, 32, 3*32*32);
  convT_bf16_kernel<<<(3*64*64+255)/256,256,0,stream>>>(W2, Wtb2, 64, 3*64*64);

  // CSR build
  zero_counts<<<(n+255)/256,256,0,stream>>>(cnt, cur, n);
  count_kernel<<<(e+255)/256,256,0,stream>>>(ei, cnt, e);
  scan1_kernel<<<nb,SCAN_BS,0,stream>>>(cnt, pre, bsum, n);
  scan2_kernel<<<1,1024,0,stream>>>(bsum, nb);
  scan3_kernel<<<(n+255)/256,256,0,stream>>>(pre, bsum, row_start, n);
  scatter_kernel<<<(e+255)/256,256,0,stream>>>(ei, ea, row_start, cur, esrc, e);

  // layer 1 (C=32)
  pad_x_kernel<<<(n*32+255)/256,256,0,stream>>>(x, hA, hAb0, n);
  {
    us* c0 = hAb0; us* c1 = hAb1;
    for (int i=0;i<3;i++){
      mgemm_mfma<32><<<gblk,256,0,stream>>>(c0, Wtb1 + i*32*32, mb, n);
      agg_kernel<32><<<((long long)n*32+255)/256,256,0,stream>>>(mb, row_start, esrc, aggb, n);
      gru_mfma<32><<<gblk,256,0,stream>>>(aggb, c0, hA, Wihb1, Whhb1, bih1, bhh1, hA, c1, n);
      us* t = c0; c0 = c1; c1 = t;
    }
  }

  transition_kernel<<<(n*64+255)/256,256,0,stream>>>(hA, hB, hBb0, n);

  // layer 2 (C=64)
  {
    us* c0 = hBb0; us* c1 = hBb1;
    for (int i=0;i<3;i++){
      mgemm_mfma<64><<<gblk,256,0,stream>>>(c0, Wtb2 + i*64*64, mb, n);
      agg_kernel<64><<<((long long)n*64+255)/256,256,0,stream>>>(mb, row_start, esrc, aggb, n);
      gru_mfma<64><<<gblk,256,0,stream>>>(aggb, c0, hB, Wihb2, Whhb2, bih2, bhh2, hB, c1, n);
      us* t = c0; c0 = c1; c1 = t;
    }
  }

  head_kernel<<<(n+511)/512,256,0,stream>>>(hB, fc1w, fc1b, fc2w, fc2b, outp, n);
}

// Round 10
// 815.696 us; speedup vs baseline: 3.9261x; 1.1209x over previous
//
#include <hip/hip_runtime.h>
#include <math.h>

#define N_NODES 100000
#define N_EDGES 1600000
#define SCAN_BS 256

typedef __attribute__((ext_vector_type(8))) short bf8_t;   // 8 bf16 in 4 VGPRs
typedef __attribute__((ext_vector_type(4))) float f4_t;

__device__ __forceinline__ float sigmoidf_(float x){ return 1.f/(1.f + expf(-x)); }
__device__ __forceinline__ float eluf_(float x){ return x > 0.f ? x : expm1f(x); }
__device__ __forceinline__ unsigned short f2bf(float x){
  unsigned u = __float_as_uint(x);
  unsigned r = u + 0x7FFFu + ((u>>16)&1u);
  return (unsigned short)(r>>16);
}
__device__ __forceinline__ float bf2f(unsigned short v){
  return __uint_as_float(((unsigned)v)<<16);
}

// ---------------- weight prep ----------------
__global__ void conv_bf16_kernel(const float* __restrict__ s, unsigned short* __restrict__ d, int n){
  int i = blockIdx.x*256 + threadIdx.x;
  if (i < n) d[i] = f2bf(s[i]);
}
// d[m][c][k] = s[m][k][c]  (out-major transposed, bf16)
__global__ void convT_bf16_kernel(const float* __restrict__ s, unsigned short* __restrict__ d, int C, int total){
  int i = blockIdx.x*256 + threadIdx.x;
  if (i < total){
    int k = i % C; int c = (i/C)%C; int m = i/(C*C);
    d[i] = f2bf(s[(size_t)m*C*C + (size_t)k*C + c]);
  }
}
// fc2: pad [10][128] -> [16][128] bf16, bias [10] -> [16] fp32
__global__ void conv_fc2_kernel(const float* __restrict__ s, const float* __restrict__ sb,
                                unsigned short* __restrict__ d, float* __restrict__ db){
  int i = blockIdx.x*256 + threadIdx.x;
  if (i < 16*128){
    int c = i/128, k = i%128;
    d[i] = (c < 10) ? f2bf(s[c*128+k]) : (unsigned short)0;
  }
  if (i < 16) db[i] = (i < 10) ? sb[i] : 0.f;
}

// ---------------- CSR build ----------------
__global__ void zero_counts(int* cnt, int* cur, int n){
  int i = blockIdx.x*blockDim.x + threadIdx.x;
  if (i < n){ cnt[i]=0; cur[i]=0; }
}
__global__ void count_kernel(const int* __restrict__ ei, int* __restrict__ cnt, int e){
  int i = blockIdx.x*blockDim.x + threadIdx.x;
  if (i < e) atomicAdd(&cnt[ei[N_EDGES + i]], 1);
}
__global__ void scan1_kernel(const int* __restrict__ cnt, int* __restrict__ pre,
                             int* __restrict__ bsum, int n){
  __shared__ int sh[SCAN_BS];
  int t = threadIdx.x, gi = blockIdx.x*SCAN_BS + t;
  int v = (gi < n) ? cnt[gi] : 0;
  sh[t] = v;
  __syncthreads();
  for (int off=1; off<SCAN_BS; off<<=1){
    int u = (t>=off)?sh[t-off]:0;
    __syncthreads();
    sh[t] += u;
    __syncthreads();
  }
  if (gi < n) pre[gi] = sh[t] - v;
  if (t == SCAN_BS-1) bsum[blockIdx.x] = sh[t];
}
__global__ void scan2_kernel(int* __restrict__ bsum, int nb){
  __shared__ int sh[1024];
  int t = threadIdx.x;
  int v = (t < nb) ? bsum[t] : 0;
  sh[t] = v;
  __syncthreads();
  for (int off=1; off<1024; off<<=1){
    int u = (t>=off)?sh[t-off]:0;
    __syncthreads();
    sh[t] += u;
    __syncthreads();
  }
  if (t < nb) bsum[t] = sh[t] - v;
}
__global__ void scan3_kernel(const int* __restrict__ pre, const int* __restrict__ bsum,
                             int* __restrict__ row_start, int n){
  int i = blockIdx.x*blockDim.x + threadIdx.x;
  if (i < n) row_start[i] = pre[i] + bsum[i/SCAN_BS];
  if (i == 0) row_start[n] = N_EDGES;
}
__global__ void scatter_kernel(const int* __restrict__ ei, const float* __restrict__ ea,
    const int* __restrict__ row_start, int* __restrict__ cur,
    int2* __restrict__ esrc, int e){
  int i = blockIdx.x*blockDim.x + threadIdx.x;
  if (i < e){
    int d = ei[N_EDGES + i];
    int p = row_start[d] + atomicAdd(&cur[d], 1);
    esrc[p] = make_int2(ei[i], __float_as_int(ea[i]));
  }
}

// ---------------- elementwise ----------------
__global__ void pad_x_kernel(const float* __restrict__ x, float* __restrict__ h,
                             unsigned short* __restrict__ hb, int n){
  int i = blockIdx.x*blockDim.x + threadIdx.x;
  if (i < n*32){
    int node = i >> 5, c = i & 31;
    float v = (c < 16) ? x[node*16 + c] : 0.f;
    h[i] = v;
    hb[i] = f2bf(v);
  }
}
__global__ void transition_kernel(const float* __restrict__ h1, float* __restrict__ h2,
                                  unsigned short* __restrict__ h2b, int n){
  int i = blockIdx.x*blockDim.x + threadIdx.x;
  if (i < n*64){
    int node = i >> 6, c = i & 63;
    float v = (c < 32) ? eluf_(h1[node*32 + c]) : 0.f;
    h2[i] = v;
    h2b[i] = f2bf(v);
  }
}

// ---------------- m = h @ W via MFMA: one wave = 16 nodes ----------------
template<int C>
__global__ __launch_bounds__(256) void mgemm_mfma(const unsigned short* __restrict__ hb,
    const unsigned short* __restrict__ Wtb, unsigned short* __restrict__ mb, int n){
  constexpr int NT = C/16, KS = C/32;
  int l = threadIdx.x & 63, w = threadIdx.x >> 6;
  int mbase = blockIdx.x*64 + w*16;
  if (mbase >= n) return;
  int lr = l & 15, lk = (l >> 4)*8;
  f4_t acc[NT];
  #pragma unroll
  for (int t=0;t<NT;t++) acc[t] = f4_t{0.f,0.f,0.f,0.f};
  #pragma unroll
  for (int ks=0; ks<KS; ks++){
    int k0 = ks*32 + lk;
    bf8_t a = *(const bf8_t*)(hb + (size_t)(mbase+lr)*C + k0);
    #pragma unroll
    for (int t=0;t<NT;t++){
      bf8_t b = *(const bf8_t*)(Wtb + (size_t)(t*16+lr)*C + k0);
      acc[t] = __builtin_amdgcn_mfma_f32_16x16x32_bf16(a, b, acc[t], 0, 0, 0);
    }
  }
  int dr = (l>>4)*4;
  #pragma unroll
  for (int t=0;t<NT;t++){
    #pragma unroll
    for (int r=0;r<4;r++){
      int node = mbase + dr + r;
      if (node < n)                       // tail guard: no write past buffer (race fix)
        mb[(size_t)node*C + t*16 + lr] = f2bf(acc[t][r]);
    }
  }
}

// ---------------- agg (bf16 in/out), 4-deep gather pipeline ----------------
template<int C>
__global__ void agg_kernel(const unsigned short* __restrict__ mb, const int* __restrict__ row_start,
    const int2* __restrict__ esrc, unsigned short* __restrict__ aggb, int n_nodes){
  int gid = blockIdx.x*blockDim.x + threadIdx.x;
  int nn = gid / C, c = gid % C;
  if (nn >= n_nodes) return;
  int s = row_start[nn], e = row_start[nn+1];
  float acc = -__builtin_inff();
  int i = s;
  for (; i+4<=e; i+=4){
    int2 e0 = esrc[i], e1 = esrc[i+1], e2 = esrc[i+2], e3 = esrc[i+3];
    float v0 = bf2f(mb[(size_t)e0.x*C + c])*__int_as_float(e0.y);
    float v1 = bf2f(mb[(size_t)e1.x*C + c])*__int_as_float(e1.y);
    float v2 = bf2f(mb[(size_t)e2.x*C + c])*__int_as_float(e2.y);
    float v3 = bf2f(mb[(size_t)e3.x*C + c])*__int_as_float(e3.y);
    acc = fmaxf(acc, fmaxf(fmaxf(v0, v1), fmaxf(v2, v3)));
  }
  for (; i<e; i++){
    int2 e0 = esrc[i];
    acc = fmaxf(acc, bf2f(mb[(size_t)e0.x*C + c])*__int_as_float(e0.y));
  }
  aggb[(size_t)nn*C+c] = (e > s) ? f2bf(acc) : (unsigned short)0;
}

// ---------------- fused GRU via MFMA ----------------
template<int C>
__global__ __launch_bounds__(256) void gru_mfma(
    const unsigned short* __restrict__ aggb, const unsigned short* __restrict__ hbin,
    const float* __restrict__ hfin,
    const unsigned short* __restrict__ Wihb, const unsigned short* __restrict__ Whhb,
    const float* __restrict__ bih, const float* __restrict__ bhh,
    float* __restrict__ hfout, unsigned short* __restrict__ hbout, int n){
  constexpr int NT = 3*C/16;
  constexpr int KS = C/32;
  constexpr int CT = C/16;
  int l = threadIdx.x & 63, w = threadIdx.x >> 6;
  int mbase = blockIdx.x*64 + w*16;
  if (mbase >= n) return;
  int lr = l & 15, lk = (l >> 4)*8;
  f4_t accI[NT], accH[NT];
  #pragma unroll
  for (int t=0;t<NT;t++){ accI[t]=f4_t{0.f,0.f,0.f,0.f}; accH[t]=f4_t{0.f,0.f,0.f,0.f}; }
  #pragma unroll
  for (int ks=0; ks<KS; ks++){
    int k0 = ks*32 + lk;
    bf8_t aI = *(const bf8_t*)(aggb + (size_t)(mbase+lr)*C + k0);
    bf8_t aH = *(const bf8_t*)(hbin + (size_t)(mbase+lr)*C + k0);
    #pragma unroll
    for (int t=0;t<NT;t++){
      bf8_t bI = *(const bf8_t*)(Wihb + (size_t)(t*16+lr)*C + k0);
      accI[t] = __builtin_amdgcn_mfma_f32_16x16x32_bf16(aI, bI, accI[t], 0, 0, 0);
      bf8_t bH = *(const bf8_t*)(Whhb + (size_t)(t*16+lr)*C + k0);
      accH[t] = __builtin_amdgcn_mfma_f32_16x16x32_bf16(aH, bH, accH[t], 0, 0, 0);
    }
  }
  int dr = (l>>4)*4;
  #pragma unroll
  for (int ct=0; ct<CT; ct++){
    int c = ct*16 + lr;
    float bR = bih[c],     cR = bhh[c];
    float bZ = bih[c+C],   cZ = bhh[c+C];
    float bN = bih[c+2*C], cN = bhh[c+2*C];
    #pragma unroll
    for (int r=0;r<4;r++){
      int i = mbase + dr + r;
      if (i < n){                          // tail guard (race fix)
        float giR = accI[ct][r] + bR,      ghR = accH[ct][r] + cR;
        float giZ = accI[CT+ct][r] + bZ,   ghZ = accH[CT+ct][r] + cZ;
        float giN = accI[2*CT+ct][r] + bN, ghN = accH[2*CT+ct][r] + cN;
        float rr = sigmoidf_(giR + ghR);
        float z  = sigmoidf_(giZ + ghZ);
        float nn = tanhf(giN + rr*ghN);
        float h  = hfin[(size_t)i*C + c];
        float ho = (1.f - z)*nn + z*h;
        hfout[(size_t)i*C + c] = ho;
        hbout[(size_t)i*C + c] = f2bf(ho);
      }
    }
  }
}

// ---------------- head via MFMA: elu -> fc1 -> elu -> fc2 -> log_softmax ----
// fc1: A = elu(h2) bf16 (built in-reg from fp32), B = fc1w rows (bf16).
// Transpose fc1 D-frag -> A-frag via per-wave LDS tile [16][136] bf16.
// fc2: N=16 (10 valid), then 16-lane shfl_xor max/sum for log_softmax.
__global__ __launch_bounds__(256) void head_mfma(const float* __restrict__ h2,
    const unsigned short* __restrict__ fc1wb, const float* __restrict__ fc1b,
    const unsigned short* __restrict__ fc2wpb, const float* __restrict__ fc2bp,
    float* __restrict__ out, int n){
  __shared__ __align__(16) unsigned short lds[4][16*136];
  int l = threadIdx.x & 63, w = threadIdx.x >> 6;
  int mbase = blockIdx.x*64 + w*16;          // no early return: barrier stays uniform
  int lr = l & 15, lk = (l >> 4)*8;
  int dr = (l>>4)*4;
  // ---- fc1 ----
  f4_t acc1[8];
  #pragma unroll
  for (int t=0;t<8;t++) acc1[t] = f4_t{0.f,0.f,0.f,0.f};
  #pragma unroll
  for (int ks=0; ks<2; ks++){
    int k0 = ks*32 + lk;
    const float* hp = h2 + (size_t)(mbase+lr)*64 + k0;   // tail rows read scratch: safe
    float4 v0 = *(const float4*)hp;
    float4 v1 = *(const float4*)(hp+4);
    bf8_t a;
    a[0]=(short)f2bf(eluf_(v0.x)); a[1]=(short)f2bf(eluf_(v0.y));
    a[2]=(short)f2bf(eluf_(v0.z)); a[3]=(short)f2bf(eluf_(v0.w));
    a[4]=(short)f2bf(eluf_(v1.x)); a[5]=(short)f2bf(eluf_(v1.y));
    a[6]=(short)f2bf(eluf_(v1.z)); a[7]=(short)f2bf(eluf_(v1.w));
    #pragma unroll
    for (int t=0;t<8;t++){
      bf8_t b = *(const bf8_t*)(fc1wb + (size_t)(t*16+lr)*64 + k0);
      acc1[t] = __builtin_amdgcn_mfma_f32_16x16x32_bf16(a, b, acc1[t], 0, 0, 0);
    }
  }
  // ---- bias + elu, transpose through LDS ----
  unsigned short* tile = lds[w];
  #pragma unroll
  for (int t=0;t<8;t++){
    float b1 = fc1b[t*16 + lr];
    #pragma unroll
    for (int r=0;r<4;r++)
      tile[(dr+r)*136 + t*16 + lr] = f2bf(eluf_(acc1[t][r] + b1));
  }
  __syncthreads();
  // ---- fc2 ----
  f4_t acc2 = f4_t{0.f,0.f,0.f,0.f};
  #pragma unroll
  for (int ks=0; ks<4; ks++){
    int k0 = ks*32 + lk;
    bf8_t a = *(const bf8_t*)(tile + lr*136 + k0);
    bf8_t b = *(const bf8_t*)(fc2wpb + (size_t)lr*128 + k0);
    acc2 = __builtin_amdgcn_mfma_f32_16x16x32_bf16(a, b, acc2, 0, 0, 0);
  }
  // ---- log_softmax over classes (16 lanes = 16 cols, 10 valid) ----
  float b2 = fc2bp[lr];
  #pragma unroll
  for (int r=0;r<4;r++){
    float val = acc2[r] + b2;
    float vm = (lr < 10) ? val : -__builtin_inff();
    #pragma unroll
    for (int m=1;m<16;m<<=1) vm = fmaxf(vm, __shfl_xor(vm, m, 64));
    float ex = (lr < 10) ? expf(val - vm) : 0.f;
    #pragma unroll
    for (int m=1;m<16;m<<=1) ex += __shfl_xor(ex, m, 64);
    float lse = vm + logf(ex);
    int node = mbase + dr + r;
    if (lr < 10 && node < n) out[(size_t)node*10 + lr] = val - lse;
  }
}

extern "C" void kernel_launch(void* const* d_in, const int* in_sizes, int n_in,
                              void* d_out, int out_size, void* d_ws, size_t ws_size,
                              hipStream_t stream){
  const float* x    = (const float*)d_in[0];
  const int*   ei   = (const int*)  d_in[1];
  const float* ea   = (const float*)d_in[2];
  const float* W1   = (const float*)d_in[3];
  const float* Wih1 = (const float*)d_in[4];
  const float* Whh1 = (const float*)d_in[5];
  const float* bih1 = (const float*)d_in[6];
  const float* bhh1 = (const float*)d_in[7];
  const float* W2   = (const float*)d_in[8];
  const float* Wih2 = (const float*)d_in[9];
  const float* Whh2 = (const float*)d_in[10];
  const float* bih2 = (const float*)d_in[11];
  const float* bhh2 = (const float*)d_in[12];
  const float* fc1w = (const float*)d_in[13];
  const float* fc1b = (const float*)d_in[14];
  const float* fc2w = (const float*)d_in[15];
  const float* fc2b = (const float*)d_in[16];
  float* outp = (float*)d_out;

  char* ws = (char*)d_ws;
  size_t off = 0;
  auto alloc = [&](size_t bytes)->void*{
    void* p = ws + off;
    off += (bytes + 255) & ~size_t(255);
    return p;
  };
  typedef unsigned short us;
  float* hA   = (float*)alloc(sizeof(float)*N_NODES*32);
  float* hB   = (float*)alloc(sizeof(float)*N_NODES*64);
  us* hAb0    = (us*)alloc(sizeof(us)*N_NODES*32);
  us* hAb1    = (us*)alloc(sizeof(us)*N_NODES*32);
  us* hBb0    = (us*)alloc(sizeof(us)*N_NODES*64);
  us* hBb1    = (us*)alloc(sizeof(us)*N_NODES*64);
  us* mb      = (us*)alloc(sizeof(us)*N_NODES*64);
  us* aggb    = (us*)alloc(sizeof(us)*N_NODES*64);
  int* row_start = (int*)alloc(sizeof(int)*(N_NODES+1));
  int* cnt    = (int*)alloc(sizeof(int)*N_NODES);
  int* cur    = (int*)alloc(sizeof(int)*N_NODES);
  int* pre    = (int*)alloc(sizeof(int)*N_NODES);
  int* bsum   = (int*)alloc(sizeof(int)*1024);
  int2* esrc  = (int2*)alloc(sizeof(int2)*N_EDGES);
  us* Wihb1   = (us*)alloc(sizeof(us)*96*32);
  us* Whhb1   = (us*)alloc(sizeof(us)*96*32);
  us* Wihb2   = (us*)alloc(sizeof(us)*192*64);
  us* Whhb2   = (us*)alloc(sizeof(us)*192*64);
  us* Wtb1    = (us*)alloc(sizeof(us)*3*32*32);
  us* Wtb2    = (us*)alloc(sizeof(us)*3*64*64);
  us* fc1wb   = (us*)alloc(sizeof(us)*128*64);
  us* fc2wpb  = (us*)alloc(sizeof(us)*16*128);
  float* fc2bp= (float*)alloc(sizeof(float)*16);
  (void)ws_size; (void)in_sizes; (void)n_in; (void)out_size;

  const int n = N_NODES, e = N_EDGES;
  const int nb = (n + SCAN_BS - 1)/SCAN_BS;
  const int gblk = (n + 63)/64;             // 1563

  // weight prep (bf16)
  conv_bf16_kernel<<<(96*32+255)/256,256,0,stream>>>(Wih1, Wihb1, 96*32);
  conv_bf16_kernel<<<(96*32+255)/256,256,0,stream>>>(Whh1, Whhb1, 96*32);
  conv_bf16_kernel<<<(192*64+255)/256,256,0,stream>>>(Wih2, Wihb2, 192*64);
  conv_bf16_kernel<<<(192*64+255)/256,256,0,stream>>>(Whh2, Whhb2, 192*64);
  convT_bf16_kernel<<<(3*32*32+255)/256,256,0,stream>>>(W1, Wtb1, 32, 3*32*32);
  convT_bf16_kernel<<<(3*64*64+255)/256,256,0,stream>>>(W2, Wtb2, 64, 3*64*64);
  conv_bf16_kernel<<<(128*64+255)/256,256,0,stream>>>(fc1w, fc1wb, 128*64);
  conv_fc2_kernel<<<(16*128+255)/256,256,0,stream>>>(fc2w, fc2b, fc2wpb, fc2bp);

  // CSR build
  zero_counts<<<(n+255)/256,256,0,stream>>>(cnt, cur, n);
  count_kernel<<<(e+255)/256,256,0,stream>>>(ei, cnt, e);
  scan1_kernel<<<nb,SCAN_BS,0,stream>>>(cnt, pre, bsum, n);
  scan2_kernel<<<1,1024,0,stream>>>(bsum, nb);
  scan3_kernel<<<(n+255)/256,256,0,stream>>>(pre, bsum, row_start, n);
  scatter_kernel<<<(e+255)/256,256,0,stream>>>(ei, ea, row_start, cur, esrc, e);

  // layer 1 (C=32)
  pad_x_kernel<<<(n*32+255)/256,256,0,stream>>>(x, hA, hAb0, n);
  {
    us* c0 = hAb0; us* c1 = hAb1;
    for (int i=0;i<3;i++){
      mgemm_mfma<32><<<gblk,256,0,stream>>>(c0, Wtb1 + i*32*32, mb, n);
      agg_kernel<32><<<((long long)n*32+255)/256,256,0,stream>>>(mb, row_start, esrc, aggb, n);
      gru_mfma<32><<<gblk,256,0,stream>>>(aggb, c0, hA, Wihb1, Whhb1, bih1, bhh1, hA, c1, n);
      us* t = c0; c0 = c1; c1 = t;
    }
  }

  transition_kernel<<<(n*64+255)/256,256,0,stream>>>(hA, hB, hBb0, n);

  // layer 2 (C=64)
  {
    us* c0 = hBb0; us* c1 = hBb1;
    for (int i=0;i<3;i++){
      mgemm_mfma<64><<<gblk,256,0,stream>>>(c0, Wtb2 + i*64*64, mb, n);
      agg_kernel<64><<<((long long)n*64+255)/256,256,0,stream>>>(mb, row_start, esrc, aggb, n);
      gru_mfma<64><<<gblk,256,0,stream>>>(aggb, c0, hB, Wihb2, Whhb2, bih2, bhh2, hB, c1, n);
      us* t = c0; c0 = c1; c1 = t;
    }
  }

  head_mfma<<<gblk,256,0,stream>>>(hB, fc1wb, fc1b, fc2wpb, fc2bp, outp, n);
}

// Round 11
// 748.525 us; speedup vs baseline: 4.2784x; 1.0897x over previous
//
#include <hip/hip_runtime.h>
#include <math.h>

#define N_NODES 100000
#define N_EDGES 1600000
#define SCAN_BS 256

typedef __attribute__((ext_vector_type(8))) short bf8_t;   // 8 bf16 in 4 VGPRs
typedef __attribute__((ext_vector_type(4))) float f4_t;

__device__ __forceinline__ float sigmoidf_(float x){ return 1.f/(1.f + expf(-x)); }
__device__ __forceinline__ float eluf_(float x){ return x > 0.f ? x : expm1f(x); }
__device__ __forceinline__ unsigned short f2bf(float x){
  unsigned u = __float_as_uint(x);
  unsigned r = u + 0x7FFFu + ((u>>16)&1u);
  return (unsigned short)(r>>16);
}
__device__ __forceinline__ float bf2f(unsigned short v){
  return __uint_as_float(((unsigned)v)<<16);
}

// ---------------- weight prep ----------------
__global__ void conv_bf16_kernel(const float* __restrict__ s, unsigned short* __restrict__ d, int n){
  int i = blockIdx.x*256 + threadIdx.x;
  if (i < n) d[i] = f2bf(s[i]);
}
// d[m][c][k] = s[m][k][c]  (out-major transposed, bf16)
__global__ void convT_bf16_kernel(const float* __restrict__ s, unsigned short* __restrict__ d, int C, int total){
  int i = blockIdx.x*256 + threadIdx.x;
  if (i < total){
    int k = i % C; int c = (i/C)%C; int m = i/(C*C);
    d[i] = f2bf(s[(size_t)m*C*C + (size_t)k*C + c]);
  }
}
// fc2: pad [10][128] -> [16][128] bf16, bias [10] -> [16] fp32
__global__ void conv_fc2_kernel(const float* __restrict__ s, const float* __restrict__ sb,
                                unsigned short* __restrict__ d, float* __restrict__ db){
  int i = blockIdx.x*256 + threadIdx.x;
  if (i < 16*128){
    int c = i/128, k = i%128;
    d[i] = (c < 10) ? f2bf(s[c*128+k]) : (unsigned short)0;
  }
  if (i < 16) db[i] = (i < 10) ? sb[i] : 0.f;
}

// ---------------- CSR build ----------------
__global__ void zero_counts(int* cnt, int* cur, int n){
  int i = blockIdx.x*blockDim.x + threadIdx.x;
  if (i < n){ cnt[i]=0; cur[i]=0; }
}
__global__ void count_kernel(const int* __restrict__ ei, int* __restrict__ cnt, int e){
  int i = blockIdx.x*blockDim.x + threadIdx.x;
  if (i < e) atomicAdd(&cnt[ei[N_EDGES + i]], 1);
}
__global__ void scan1_kernel(const int* __restrict__ cnt, int* __restrict__ pre,
                             int* __restrict__ bsum, int n){
  __shared__ int sh[SCAN_BS];
  int t = threadIdx.x, gi = blockIdx.x*SCAN_BS + t;
  int v = (gi < n) ? cnt[gi] : 0;
  sh[t] = v;
  __syncthreads();
  for (int off=1; off<SCAN_BS; off<<=1){
    int u = (t>=off)?sh[t-off]:0;
    __syncthreads();
    sh[t] += u;
    __syncthreads();
  }
  if (gi < n) pre[gi] = sh[t] - v;
  if (t == SCAN_BS-1) bsum[blockIdx.x] = sh[t];
}
__global__ void scan2_kernel(int* __restrict__ bsum, int nb){
  __shared__ int sh[1024];
  int t = threadIdx.x;
  int v = (t < nb) ? bsum[t] : 0;
  sh[t] = v;
  __syncthreads();
  for (int off=1; off<1024; off<<=1){
    int u = (t>=off)?sh[t-off]:0;
    __syncthreads();
    sh[t] += u;
    __syncthreads();
  }
  if (t < nb) bsum[t] = sh[t] - v;
}
__global__ void scan3_kernel(const int* __restrict__ pre, const int* __restrict__ bsum,
                             int* __restrict__ row_start, int n){
  int i = blockIdx.x*blockDim.x + threadIdx.x;
  if (i < n) row_start[i] = pre[i] + bsum[i/SCAN_BS];
  if (i == 0) row_start[n] = N_EDGES;
}
__global__ void scatter_kernel(const int* __restrict__ ei, const float* __restrict__ ea,
    const int* __restrict__ row_start, int* __restrict__ cur,
    int2* __restrict__ esrc, int e){
  int i = blockIdx.x*blockDim.x + threadIdx.x;
  if (i < e){
    int d = ei[N_EDGES + i];
    int p = row_start[d] + atomicAdd(&cur[d], 1);
    esrc[p] = make_int2(ei[i], __float_as_int(ea[i]));
  }
}

// ---------------- elementwise ----------------
__global__ void pad_x_kernel(const float* __restrict__ x, float* __restrict__ h,
                             unsigned short* __restrict__ hb, int n){
  int i = blockIdx.x*blockDim.x + threadIdx.x;
  if (i < n*32){
    int node = i >> 5, c = i & 31;
    float v = (c < 16) ? x[node*16 + c] : 0.f;
    h[i] = v;
    hb[i] = f2bf(v);
  }
}
__global__ void transition_kernel(const float* __restrict__ h1, float* __restrict__ h2,
                                  unsigned short* __restrict__ h2b, int n){
  int i = blockIdx.x*blockDim.x + threadIdx.x;
  if (i < n*64){
    int node = i >> 6, c = i & 63;
    float v = (c < 32) ? eluf_(h1[node*32 + c]) : 0.f;
    h2[i] = v;
    h2b[i] = f2bf(v);
  }
}

// ---------------- m = h @ W via MFMA: one wave = 16 nodes ----------------
template<int C>
__global__ __launch_bounds__(256) void mgemm_mfma(const unsigned short* __restrict__ hb,
    const unsigned short* __restrict__ Wtb, unsigned short* __restrict__ mb, int n){
  constexpr int NT = C/16, KS = C/32;
  int l = threadIdx.x & 63, w = threadIdx.x >> 6;
  int mbase = blockIdx.x*64 + w*16;
  if (mbase >= n) return;
  int lr = l & 15, lk = (l >> 4)*8;
  f4_t acc[NT];
  #pragma unroll
  for (int t=0;t<NT;t++) acc[t] = f4_t{0.f,0.f,0.f,0.f};
  #pragma unroll
  for (int ks=0; ks<KS; ks++){
    int k0 = ks*32 + lk;
    bf8_t a = *(const bf8_t*)(hb + (size_t)(mbase+lr)*C + k0);
    #pragma unroll
    for (int t=0;t<NT;t++){
      bf8_t b = *(const bf8_t*)(Wtb + (size_t)(t*16+lr)*C + k0);
      acc[t] = __builtin_amdgcn_mfma_f32_16x16x32_bf16(a, b, acc[t], 0, 0, 0);
    }
  }
  int dr = (l>>4)*4;
  #pragma unroll
  for (int t=0;t<NT;t++){
    #pragma unroll
    for (int r=0;r<4;r++){
      int node = mbase + dr + r;
      if (node < n)                       // tail guard: no write past buffer (race fix)
        mb[(size_t)node*C + t*16 + lr] = f2bf(acc[t][r]);
    }
  }
}

// ---------------- agg: 8 channels/lane via uint4 gathers ----------------
// lane group (C/8 lanes) per node; 16B loads put 8x bytes in flight vs ushort.
template<int C>
__global__ void agg_kernel(const unsigned short* __restrict__ mb, const int* __restrict__ row_start,
    const int2* __restrict__ esrc, unsigned short* __restrict__ aggb, int n_nodes){
  constexpr int GPN = C/8;
  int gid = blockIdx.x*blockDim.x + threadIdx.x;
  int nn = gid / GPN, g8 = gid % GPN;
  if (nn >= n_nodes) return;
  int s = row_start[nn], e = row_start[nn+1];
  float acc[8];
  #pragma unroll
  for (int j=0;j<8;j++) acc[j] = -__builtin_inff();
  const unsigned short* mbg = mb + g8*8;
  int i = s;
  for (; i+2<=e; i+=2){
    int2 e0 = esrc[i], e1 = esrc[i+1];
    uint4 v0 = *(const uint4*)(mbg + (size_t)e0.x*C);
    uint4 v1 = *(const uint4*)(mbg + (size_t)e1.x*C);
    float w0 = __int_as_float(e0.y), w1 = __int_as_float(e1.y);
    unsigned a0[4] = {v0.x, v0.y, v0.z, v0.w};
    unsigned a1[4] = {v1.x, v1.y, v1.z, v1.w};
    #pragma unroll
    for (int q=0;q<4;q++){
      float lo0 = __uint_as_float(a0[q]<<16), hi0 = __uint_as_float(a0[q]&0xFFFF0000u);
      float lo1 = __uint_as_float(a1[q]<<16), hi1 = __uint_as_float(a1[q]&0xFFFF0000u);
      acc[2*q]   = fmaxf(acc[2*q],   fmaxf(lo0*w0, lo1*w1));
      acc[2*q+1] = fmaxf(acc[2*q+1], fmaxf(hi0*w0, hi1*w1));
    }
  }
  if (i < e){
    int2 e0 = esrc[i];
    uint4 v0 = *(const uint4*)(mbg + (size_t)e0.x*C);
    float w0 = __int_as_float(e0.y);
    unsigned a0[4] = {v0.x, v0.y, v0.z, v0.w};
    #pragma unroll
    for (int q=0;q<4;q++){
      float lo0 = __uint_as_float(a0[q]<<16), hi0 = __uint_as_float(a0[q]&0xFFFF0000u);
      acc[2*q]   = fmaxf(acc[2*q],   lo0*w0);
      acc[2*q+1] = fmaxf(acc[2*q+1], hi0*w0);
    }
  }
  unsigned r[8];
  #pragma unroll
  for (int j=0;j<8;j++) r[j] = (e > s) ? (unsigned)f2bf(acc[j]) : 0u;
  uint4 o;
  o.x = r[0] | (r[1]<<16); o.y = r[2] | (r[3]<<16);
  o.z = r[4] | (r[5]<<16); o.w = r[6] | (r[7]<<16);
  *(uint4*)(aggb + (size_t)nn*C + g8*8) = o;
}

// ---------------- fused GRU via MFMA ----------------
template<int C>
__global__ __launch_bounds__(256) void gru_mfma(
    const unsigned short* __restrict__ aggb, const unsigned short* __restrict__ hbin,
    const float* __restrict__ hfin,
    const unsigned short* __restrict__ Wihb, const unsigned short* __restrict__ Whhb,
    const float* __restrict__ bih, const float* __restrict__ bhh,
    float* __restrict__ hfout, unsigned short* __restrict__ hbout, int n){
  constexpr int NT = 3*C/16;
  constexpr int KS = C/32;
  constexpr int CT = C/16;
  int l = threadIdx.x & 63, w = threadIdx.x >> 6;
  int mbase = blockIdx.x*64 + w*16;
  if (mbase >= n) return;
  int lr = l & 15, lk = (l >> 4)*8;
  f4_t accI[NT], accH[NT];
  #pragma unroll
  for (int t=0;t<NT;t++){ accI[t]=f4_t{0.f,0.f,0.f,0.f}; accH[t]=f4_t{0.f,0.f,0.f,0.f}; }
  #pragma unroll
  for (int ks=0; ks<KS; ks++){
    int k0 = ks*32 + lk;
    bf8_t aI = *(const bf8_t*)(aggb + (size_t)(mbase+lr)*C + k0);
    bf8_t aH = *(const bf8_t*)(hbin + (size_t)(mbase+lr)*C + k0);
    #pragma unroll
    for (int t=0;t<NT;t++){
      bf8_t bI = *(const bf8_t*)(Wihb + (size_t)(t*16+lr)*C + k0);
      accI[t] = __builtin_amdgcn_mfma_f32_16x16x32_bf16(aI, bI, accI[t], 0, 0, 0);
      bf8_t bH = *(const bf8_t*)(Whhb + (size_t)(t*16+lr)*C + k0);
      accH[t] = __builtin_amdgcn_mfma_f32_16x16x32_bf16(aH, bH, accH[t], 0, 0, 0);
    }
  }
  int dr = (l>>4)*4;
  #pragma unroll
  for (int ct=0; ct<CT; ct++){
    int c = ct*16 + lr;
    float bR = bih[c],     cR = bhh[c];
    float bZ = bih[c+C],   cZ = bhh[c+C];
    float bN = bih[c+2*C], cN = bhh[c+2*C];
    #pragma unroll
    for (int r=0;r<4;r++){
      int i = mbase + dr + r;
      if (i < n){                          // tail guard (race fix)
        float giR = accI[ct][r] + bR,      ghR = accH[ct][r] + cR;
        float giZ = accI[CT+ct][r] + bZ,   ghZ = accH[CT+ct][r] + cZ;
        float giN = accI[2*CT+ct][r] + bN, ghN = accH[2*CT+ct][r] + cN;
        float rr = sigmoidf_(giR + ghR);
        float z  = sigmoidf_(giZ + ghZ);
        float nn = tanhf(giN + rr*ghN);
        float h  = hfin[(size_t)i*C + c];
        float ho = (1.f - z)*nn + z*h;
        hfout[(size_t)i*C + c] = ho;
        hbout[(size_t)i*C + c] = f2bf(ho);
      }
    }
  }
}

// ---------------- head via MFMA: elu -> fc1 -> elu -> fc2 -> log_softmax ----
__global__ __launch_bounds__(256) void head_mfma(const float* __restrict__ h2,
    const unsigned short* __restrict__ fc1wb, const float* __restrict__ fc1b,
    const unsigned short* __restrict__ fc2wpb, const float* __restrict__ fc2bp,
    float* __restrict__ out, int n){
  __shared__ __align__(16) unsigned short lds[4][16*136];
  int l = threadIdx.x & 63, w = threadIdx.x >> 6;
  int mbase = blockIdx.x*64 + w*16;          // no early return: barrier stays uniform
  int lr = l & 15, lk = (l >> 4)*8;
  int dr = (l>>4)*4;
  // ---- fc1 ----
  f4_t acc1[8];
  #pragma unroll
  for (int t=0;t<8;t++) acc1[t] = f4_t{0.f,0.f,0.f,0.f};
  #pragma unroll
  for (int ks=0; ks<2; ks++){
    int k0 = ks*32 + lk;
    const float* hp = h2 + (size_t)(mbase+lr)*64 + k0;   // tail rows read scratch: safe
    float4 v0 = *(const float4*)hp;
    float4 v1 = *(const float4*)(hp+4);
    bf8_t a;
    a[0]=(short)f2bf(eluf_(v0.x)); a[1]=(short)f2bf(eluf_(v0.y));
    a[2]=(short)f2bf(eluf_(v0.z)); a[3]=(short)f2bf(eluf_(v0.w));
    a[4]=(short)f2bf(eluf_(v1.x)); a[5]=(short)f2bf(eluf_(v1.y));
    a[6]=(short)f2bf(eluf_(v1.z)); a[7]=(short)f2bf(eluf_(v1.w));
    #pragma unroll
    for (int t=0;t<8;t++){
      bf8_t b = *(const bf8_t*)(fc1wb + (size_t)(t*16+lr)*64 + k0);
      acc1[t] = __builtin_amdgcn_mfma_f32_16x16x32_bf16(a, b, acc1[t], 0, 0, 0);
    }
  }
  // ---- bias + elu, transpose through LDS ----
  unsigned short* tile = lds[w];
  #pragma unroll
  for (int t=0;t<8;t++){
    float b1 = fc1b[t*16 + lr];
    #pragma unroll
    for (int r=0;r<4;r++)
      tile[(dr+r)*136 + t*16 + lr] = f2bf(eluf_(acc1[t][r] + b1));
  }
  __syncthreads();
  // ---- fc2 ----
  f4_t acc2 = f4_t{0.f,0.f,0.f,0.f};
  #pragma unroll
  for (int ks=0; ks<4; ks++){
    int k0 = ks*32 + lk;
    bf8_t a = *(const bf8_t*)(tile + lr*136 + k0);
    bf8_t b = *(const bf8_t*)(fc2wpb + (size_t)lr*128 + k0);
    acc2 = __builtin_amdgcn_mfma_f32_16x16x32_bf16(a, b, acc2, 0, 0, 0);
  }
  // ---- log_softmax over classes (16 lanes = 16 cols, 10 valid) ----
  float b2 = fc2bp[lr];
  #pragma unroll
  for (int r=0;r<4;r++){
    float val = acc2[r] + b2;
    float vm = (lr < 10) ? val : -__builtin_inff();
    #pragma unroll
    for (int m=1;m<16;m<<=1) vm = fmaxf(vm, __shfl_xor(vm, m, 64));
    float ex = (lr < 10) ? expf(val - vm) : 0.f;
    #pragma unroll
    for (int m=1;m<16;m<<=1) ex += __shfl_xor(ex, m, 64);
    float lse = vm + logf(ex);
    int node = mbase + dr + r;
    if (lr < 10 && node < n) out[(size_t)node*10 + lr] = val - lse;
  }
}

extern "C" void kernel_launch(void* const* d_in, const int* in_sizes, int n_in,
                              void* d_out, int out_size, void* d_ws, size_t ws_size,
                              hipStream_t stream){
  const float* x    = (const float*)d_in[0];
  const int*   ei   = (const int*)  d_in[1];
  const float* ea   = (const float*)d_in[2];
  const float* W1   = (const float*)d_in[3];
  const float* Wih1 = (const float*)d_in[4];
  const float* Whh1 = (const float*)d_in[5];
  const float* bih1 = (const float*)d_in[6];
  const float* bhh1 = (const float*)d_in[7];
  const float* W2   = (const float*)d_in[8];
  const float* Wih2 = (const float*)d_in[9];
  const float* Whh2 = (const float*)d_in[10];
  const float* bih2 = (const float*)d_in[11];
  const float* bhh2 = (const float*)d_in[12];
  const float* fc1w = (const float*)d_in[13];
  const float* fc1b = (const float*)d_in[14];
  const float* fc2w = (const float*)d_in[15];
  const float* fc2b = (const float*)d_in[16];
  float* outp = (float*)d_out;

  char* ws = (char*)d_ws;
  size_t off = 0;
  auto alloc = [&](size_t bytes)->void*{
    void* p = ws + off;
    off += (bytes + 255) & ~size_t(255);
    return p;
  };
  typedef unsigned short us;
  float* hA   = (float*)alloc(sizeof(float)*N_NODES*32);
  float* hB   = (float*)alloc(sizeof(float)*N_NODES*64);
  us* hAb0    = (us*)alloc(sizeof(us)*N_NODES*32);
  us* hAb1    = (us*)alloc(sizeof(us)*N_NODES*32);
  us* hBb0    = (us*)alloc(sizeof(us)*N_NODES*64);
  us* hBb1    = (us*)alloc(sizeof(us)*N_NODES*64);
  us* mb      = (us*)alloc(sizeof(us)*N_NODES*64);
  us* aggb    = (us*)alloc(sizeof(us)*N_NODES*64);
  int* row_start = (int*)alloc(sizeof(int)*(N_NODES+1));
  int* cnt    = (int*)alloc(sizeof(int)*N_NODES);
  int* cur    = (int*)alloc(sizeof(int)*N_NODES);
  int* pre    = (int*)alloc(sizeof(int)*N_NODES);
  int* bsum   = (int*)alloc(sizeof(int)*1024);
  int2* esrc  = (int2*)alloc(sizeof(int2)*N_EDGES);
  us* Wihb1   = (us*)alloc(sizeof(us)*96*32);
  us* Whhb1   = (us*)alloc(sizeof(us)*96*32);
  us* Wihb2   = (us*)alloc(sizeof(us)*192*64);
  us* Whhb2   = (us*)alloc(sizeof(us)*192*64);
  us* Wtb1    = (us*)alloc(sizeof(us)*3*32*32);
  us* Wtb2    = (us*)alloc(sizeof(us)*3*64*64);
  us* fc1wb   = (us*)alloc(sizeof(us)*128*64);
  us* fc2wpb  = (us*)alloc(sizeof(us)*16*128);
  float* fc2bp= (float*)alloc(sizeof(float)*16);
  (void)ws_size; (void)in_sizes; (void)n_in; (void)out_size;

  const int n = N_NODES, e = N_EDGES;
  const int nb = (n + SCAN_BS - 1)/SCAN_BS;
  const int gblk = (n + 63)/64;             // 1563

  // weight prep (bf16)
  conv_bf16_kernel<<<(96*32+255)/256,256,0,stream>>>(Wih1, Wihb1, 96*32);
  conv_bf16_kernel<<<(96*32+255)/256,256,0,stream>>>(Whh1, Whhb1, 96*32);
  conv_bf16_kernel<<<(192*64+255)/256,256,0,stream>>>(Wih2, Wihb2, 192*64);
  conv_bf16_kernel<<<(192*64+255)/256,256,0,stream>>>(Whh2, Whhb2, 192*64);
  convT_bf16_kernel<<<(3*32*32+255)/256,256,0,stream>>>(W1, Wtb1, 32, 3*32*32);
  convT_bf16_kernel<<<(3*64*64+255)/256,256,0,stream>>>(W2, Wtb2, 64, 3*64*64);
  conv_bf16_kernel<<<(128*64+255)/256,256,0,stream>>>(fc1w, fc1wb, 128*64);
  conv_fc2_kernel<<<(16*128+255)/256,256,0,stream>>>(fc2w, fc2b, fc2wpb, fc2bp);

  // CSR build
  zero_counts<<<(n+255)/256,256,0,stream>>>(cnt, cur, n);
  count_kernel<<<(e+255)/256,256,0,stream>>>(ei, cnt, e);
  scan1_kernel<<<nb,SCAN_BS,0,stream>>>(cnt, pre, bsum, n);
  scan2_kernel<<<1,1024,0,stream>>>(bsum, nb);
  scan3_kernel<<<(n+255)/256,256,0,stream>>>(pre, bsum, row_start, n);
  scatter_kernel<<<(e+255)/256,256,0,stream>>>(ei, ea, row_start, cur, esrc, e);

  // layer 1 (C=32)
  pad_x_kernel<<<(n*32+255)/256,256,0,stream>>>(x, hA, hAb0, n);
  {
    us* c0 = hAb0; us* c1 = hAb1;
    for (int i=0;i<3;i++){
      mgemm_mfma<32><<<gblk,256,0,stream>>>(c0, Wtb1 + i*32*32, mb, n);
      agg_kernel<32><<<((long long)n*4+255)/256,256,0,stream>>>(mb, row_start, esrc, aggb, n);
      gru_mfma<32><<<gblk,256,0,stream>>>(aggb, c0, hA, Wihb1, Whhb1, bih1, bhh1, hA, c1, n);
      us* t = c0; c0 = c1; c1 = t;
    }
  }

  transition_kernel<<<(n*64+255)/256,256,0,stream>>>(hA, hB, hBb0, n);

  // layer 2 (C=64)
  {
    us* c0 = hBb0; us* c1 = hBb1;
    for (int i=0;i<3;i++){
      mgemm_mfma<64><<<gblk,256,0,stream>>>(c0, Wtb2 + i*64*64, mb, n);
      agg_kernel<64><<<((long long)n*8+255)/256,256,0,stream>>>(mb, row_start, esrc, aggb, n);
      gru_mfma<64><<<gblk,256,0,stream>>>(aggb, c0, hB, Wihb2, Whhb2, bih2, bhh2, hB, c1, n);
      us* t = c0; c0 = c1; c1 = t;
    }
  }

  head_mfma<<<gblk,256,0,stream>>>(hB, fc1wb, fc1b, fc2wpb, fc2bp, outp, n);
}

// Round 13
// 716.594 us; speedup vs baseline: 4.4690x; 1.0446x over previous
//
#include <hip/hip_runtime.h>
#include <math.h>

#define N_NODES 100000
#define N_EDGES 1600000
#define SCAN_BS 256

typedef __attribute__((ext_vector_type(8))) short bf8_t;   // 8 bf16 in 4 VGPRs
typedef __attribute__((ext_vector_type(4))) float f4_t;
typedef unsigned short us;

__device__ __forceinline__ float sigmoidf_(float x){ return 1.f/(1.f + expf(-x)); }
__device__ __forceinline__ float eluf_(float x){ return x > 0.f ? x : expm1f(x); }
__device__ __forceinline__ us f2bf(float x){
  unsigned u = __float_as_uint(x);
  unsigned r = u + 0x7FFFu + ((u>>16)&1u);
  return (us)(r>>16);
}
__device__ __forceinline__ float bf2f(us v){
  return __uint_as_float(((unsigned)v)<<16);
}

// ---------------- fused weight prep (one kernel, segment-dispatched) ----------
__global__ void prep_all(const float* __restrict__ Wih1, const float* __restrict__ Whh1,
                         const float* __restrict__ Wih2, const float* __restrict__ Whh2,
                         const float* __restrict__ W1,   const float* __restrict__ W2,
                         const float* __restrict__ fc1w, const float* __restrict__ fc2w,
                         const float* __restrict__ fc2b,
                         us* Wihb1, us* Whhb1, us* Wihb2, us* Whhb2,
                         us* Wtb1, us* Wtb2, us* fc1wb, us* fc2wpb, float* fc2bp){
  int i = blockIdx.x*256 + threadIdx.x;
  if (i < 3072) { Wihb1[i]=f2bf(Wih1[i]); return; } i -= 3072;
  if (i < 3072) { Whhb1[i]=f2bf(Whh1[i]); return; } i -= 3072;
  if (i < 12288){ Wihb2[i]=f2bf(Wih2[i]); return; } i -= 12288;
  if (i < 12288){ Whhb2[i]=f2bf(Whh2[i]); return; } i -= 12288;
  if (i < 3072) { int k=i%32, c=(i/32)%32, m=i/1024;           // Wt[m][c][k] = W[m][k][c]
                  Wtb1[i]=f2bf(W1[m*1024 + k*32 + c]); return; } i -= 3072;
  if (i < 12288){ int k=i%64, c=(i/64)%64, m=i/4096;
                  Wtb2[i]=f2bf(W2[m*4096 + k*64 + c]); return; } i -= 12288;
  if (i < 8192) { fc1wb[i]=f2bf(fc1w[i]); return; } i -= 8192;
  if (i < 2048) { int c=i/128, k=i%128;
                  fc2wpb[i]=(c<10)?f2bf(fc2w[c*128+k]):(us)0; return; } i -= 2048;
  if (i < 16)   { fc2bp[i] = (i<10)? fc2b[i] : 0.f; }
}

// ---------------- CSR build ----------------
__global__ void zero_counts(int* cnt, int* cur, int n){
  int i = blockIdx.x*blockDim.x + threadIdx.x;
  if (i < n){ cnt[i]=0; cur[i]=0; }
}
__global__ void count_kernel(const int* __restrict__ ei, int* __restrict__ cnt, int e){
  int i = blockIdx.x*blockDim.x + threadIdx.x;
  if (i < e) atomicAdd(&cnt[ei[N_EDGES + i]], 1);
}
__global__ void scan1_kernel(const int* __restrict__ cnt, int* __restrict__ pre,
                             int* __restrict__ bsum, int n){
  __shared__ int sh[SCAN_BS];
  int t = threadIdx.x, gi = blockIdx.x*SCAN_BS + t;
  int v = (gi < n) ? cnt[gi] : 0;
  sh[t] = v;
  __syncthreads();
  for (int off=1; off<SCAN_BS; off<<=1){
    int u = (t>=off)?sh[t-off]:0;
    __syncthreads();
    sh[t] += u;
    __syncthreads();
  }
  if (gi < n) pre[gi] = sh[t] - v;
  if (t == SCAN_BS-1) bsum[blockIdx.x] = sh[t];
}
__global__ void scan2_kernel(int* __restrict__ bsum, int nb){
  __shared__ int sh[1024];
  int t = threadIdx.x;
  int v = (t < nb) ? bsum[t] : 0;
  sh[t] = v;
  __syncthreads();
  for (int off=1; off<1024; off<<=1){
    int u = (t>=off)?sh[t-off]:0;
    __syncthreads();
    sh[t] += u;
    __syncthreads();
  }
  if (t < nb) bsum[t] = sh[t] - v;
}
__global__ void scan3_kernel(const int* __restrict__ pre, const int* __restrict__ bsum,
                             int* __restrict__ row_start, int n){
  int i = blockIdx.x*blockDim.x + threadIdx.x;
  if (i < n) row_start[i] = pre[i] + bsum[i/SCAN_BS];
  if (i == 0) row_start[n] = N_EDGES;
}
// 2 edges/thread, nontemporal scattered store via long long (packed {src, ew})
__global__ void scatter_kernel(const int* __restrict__ ei, const float* __restrict__ ea,
    const int* __restrict__ row_start, int* __restrict__ cur,
    long long* __restrict__ esrc, int e){
  int i0 = (blockIdx.x*blockDim.x + threadIdx.x)*2;
  #pragma unroll
  for (int j=0;j<2;j++){
    int i = i0 + j;
    if (i < e){
      int d = ei[N_EDGES + i];
      int p = row_start[d] + atomicAdd(&cur[d], 1);
      long long v = (long long)(unsigned)ei[i]
                  | ((long long)(unsigned)__float_as_int(ea[i]) << 32);
      __builtin_nontemporal_store(v, &esrc[p]);
    }
  }
}

// ---------------- elementwise ----------------
__global__ void pad_x_kernel(const float* __restrict__ x, float* __restrict__ h,
                             us* __restrict__ hb, int n){
  int i = blockIdx.x*blockDim.x + threadIdx.x;
  if (i < n*32){
    int node = i >> 5, c = i & 31;
    float v = (c < 16) ? x[node*16 + c] : 0.f;
    h[i] = v;
    hb[i] = f2bf(v);
  }
}
__global__ void transition_kernel(const float* __restrict__ h1, float* __restrict__ h2,
                                  us* __restrict__ h2b, int n){
  int i = blockIdx.x*blockDim.x + threadIdx.x;
  if (i < n*64){
    int node = i >> 6, c = i & 63;
    float v = (c < 32) ? eluf_(h1[node*32 + c]) : 0.f;
    h2[i] = v;
    h2b[i] = f2bf(v);
  }
}

// ---------------- m = h @ W via MFMA (layer-start only) ----------------
template<int C>
__global__ __launch_bounds__(256) void mgemm_mfma(const us* __restrict__ hb,
    const us* __restrict__ Wtb, us* __restrict__ mb, int n){
  constexpr int NT = C/16, KS = C/32;
  int l = threadIdx.x & 63, w = threadIdx.x >> 6;
  int mbase = blockIdx.x*64 + w*16;
  if (mbase >= n) return;
  int lr = l & 15, lk = (l >> 4)*8;
  f4_t acc[NT];
  #pragma unroll
  for (int t=0;t<NT;t++) acc[t] = f4_t{0.f,0.f,0.f,0.f};
  #pragma unroll
  for (int ks=0; ks<KS; ks++){
    int k0 = ks*32 + lk;
    bf8_t a = *(const bf8_t*)(hb + (size_t)(mbase+lr)*C + k0);
    #pragma unroll
    for (int t=0;t<NT;t++){
      bf8_t b = *(const bf8_t*)(Wtb + (size_t)(t*16+lr)*C + k0);
      acc[t] = __builtin_amdgcn_mfma_f32_16x16x32_bf16(a, b, acc[t], 0, 0, 0);
    }
  }
  int dr = (l>>4)*4;
  #pragma unroll
  for (int t=0;t<NT;t++){
    #pragma unroll
    for (int r=0;r<4;r++){
      int node = mbase + dr + r;
      if (node < n)
        mb[(size_t)node*C + t*16 + lr] = f2bf(acc[t][r]);
    }
  }
}

// ---------------- agg: 8 channels/lane via uint4 gathers, 4-deep pipeline ----
template<int C>
__global__ void agg_kernel(const us* __restrict__ mb, const int* __restrict__ row_start,
    const long long* __restrict__ esrc, us* __restrict__ aggb, int n_nodes){
  constexpr int GPN = C/8;
  int gid = blockIdx.x*blockDim.x + threadIdx.x;
  int nn = gid / GPN, g8 = gid % GPN;
  if (nn >= n_nodes) return;
  int s = row_start[nn], e = row_start[nn+1];
  float acc[8];
  #pragma unroll
  for (int j=0;j<8;j++) acc[j] = -__builtin_inff();
  const us* mbg = mb + g8*8;
  int i = s;
  for (; i+4<=e; i+=4){
    long long e0 = esrc[i], e1 = esrc[i+1], e2 = esrc[i+2], e3 = esrc[i+3];
    uint4 v0 = *(const uint4*)(mbg + (size_t)(unsigned)(e0 & 0xFFFFFFFF)*C);
    uint4 v1 = *(const uint4*)(mbg + (size_t)(unsigned)(e1 & 0xFFFFFFFF)*C);
    uint4 v2 = *(const uint4*)(mbg + (size_t)(unsigned)(e2 & 0xFFFFFFFF)*C);
    uint4 v3 = *(const uint4*)(mbg + (size_t)(unsigned)(e3 & 0xFFFFFFFF)*C);
    float w0 = __int_as_float((int)(e0>>32)), w1 = __int_as_float((int)(e1>>32));
    float w2 = __int_as_float((int)(e2>>32)), w3 = __int_as_float((int)(e3>>32));
    unsigned a0[4] = {v0.x, v0.y, v0.z, v0.w};
    unsigned a1[4] = {v1.x, v1.y, v1.z, v1.w};
    unsigned a2[4] = {v2.x, v2.y, v2.z, v2.w};
    unsigned a3[4] = {v3.x, v3.y, v3.z, v3.w};
    #pragma unroll
    for (int q=0;q<4;q++){
      float x0 = fmaxf(__uint_as_float(a0[q]<<16)*w0, __uint_as_float(a1[q]<<16)*w1);
      float x1 = fmaxf(__uint_as_float(a2[q]<<16)*w2, __uint_as_float(a3[q]<<16)*w3);
      float y0 = fmaxf(__uint_as_float(a0[q]&0xFFFF0000u)*w0, __uint_as_float(a1[q]&0xFFFF0000u)*w1);
      float y1 = fmaxf(__uint_as_float(a2[q]&0xFFFF0000u)*w2, __uint_as_float(a3[q]&0xFFFF0000u)*w3);
      acc[2*q]   = fmaxf(acc[2*q],   fmaxf(x0, x1));
      acc[2*q+1] = fmaxf(acc[2*q+1], fmaxf(y0, y1));
    }
  }
  for (; i<e; i++){
    long long e0 = esrc[i];
    uint4 v0 = *(const uint4*)(mbg + (size_t)(unsigned)(e0 & 0xFFFFFFFF)*C);
    float w0 = __int_as_float((int)(e0>>32));
    unsigned a0[4] = {v0.x, v0.y, v0.z, v0.w};
    #pragma unroll
    for (int q=0;q<4;q++){
      acc[2*q]   = fmaxf(acc[2*q],   __uint_as_float(a0[q]<<16)*w0);
      acc[2*q+1] = fmaxf(acc[2*q+1], __uint_as_float(a0[q]&0xFFFF0000u)*w0);
    }
  }
  unsigned r[8];
  #pragma unroll
  for (int j=0;j<8;j++) r[j] = (e > s) ? (unsigned)f2bf(acc[j]) : 0u;
  uint4 o;
  o.x = r[0] | (r[1]<<16); o.y = r[2] | (r[3]<<16);
  o.z = r[4] | (r[5]<<16); o.w = r[6] | (r[7]<<16);
  *(uint4*)(aggb + (size_t)nn*C + g8*8) = o;
}

// ---------------- fused GRU via MFMA; optionally computes next-iter m ------
// COMPUTE_M: transpose h (D-frag) through per-wave LDS tile -> A-frag, then
// m = h @ Wt_next (head_mfma-proven transpose pattern). No early return:
// barrier stays uniform; tail reads hit adjacent ws (safe); writes guarded.
template<int C, bool COMPUTE_M>
__global__ __launch_bounds__(256) void gru_mfma(
    const us* __restrict__ aggb, const us* __restrict__ hbin,
    const float* __restrict__ hfin,
    const us* __restrict__ Wihb, const us* __restrict__ Whhb,
    const float* __restrict__ bih, const float* __restrict__ bhh,
    const us* __restrict__ Wtb_next,
    float* __restrict__ hfout, us* __restrict__ hbout, us* __restrict__ mbout, int n){
  constexpr int NT = 3*C/16;
  constexpr int KS = C/32;
  constexpr int CT = C/16;
  constexpr int TST = C + 8;                     // LDS tile stride (bf16)
  constexpr int TSZ = COMPUTE_M ? 16*TST : 1;
  __shared__ us tlds[4][TSZ];
  int l = threadIdx.x & 63, w = threadIdx.x >> 6;
  int mbase = blockIdx.x*64 + w*16;
  int lr = l & 15, lk = (l >> 4)*8;
  f4_t accI[NT], accH[NT];
  #pragma unroll
  for (int t=0;t<NT;t++){ accI[t]=f4_t{0.f,0.f,0.f,0.f}; accH[t]=f4_t{0.f,0.f,0.f,0.f}; }
  #pragma unroll
  for (int ks=0; ks<KS; ks++){
    int k0 = ks*32 + lk;
    bf8_t aI = *(const bf8_t*)(aggb + (size_t)(mbase+lr)*C + k0);
    bf8_t aH = *(const bf8_t*)(hbin + (size_t)(mbase+lr)*C + k0);
    #pragma unroll
    for (int t=0;t<NT;t++){
      bf8_t bI = *(const bf8_t*)(Wihb + (size_t)(t*16+lr)*C + k0);
      accI[t] = __builtin_amdgcn_mfma_f32_16x16x32_bf16(aI, bI, accI[t], 0, 0, 0);
      bf8_t bH = *(const bf8_t*)(Whhb + (size_t)(t*16+lr)*C + k0);
      accH[t] = __builtin_amdgcn_mfma_f32_16x16x32_bf16(aH, bH, accH[t], 0, 0, 0);
    }
  }
  int dr = (l>>4)*4;
  us* tile = tlds[w];
  #pragma unroll
  for (int ct=0; ct<CT; ct++){
    int c = ct*16 + lr;
    float bR = bih[c],     cR = bhh[c];
    float bZ = bih[c+C],   cZ = bhh[c+C];
    float bN = bih[c+2*C], cN = bhh[c+2*C];
    #pragma unroll
    for (int r=0;r<4;r++){
      int i = mbase + dr + r;
      float giR = accI[ct][r] + bR,      ghR = accH[ct][r] + cR;
      float giZ = accI[CT+ct][r] + bZ,   ghZ = accH[CT+ct][r] + cZ;
      float giN = accI[2*CT+ct][r] + bN, ghN = accH[2*CT+ct][r] + cN;
      float rr = sigmoidf_(giR + ghR);
      float z  = sigmoidf_(giZ + ghZ);
      float nn = tanhf(giN + rr*ghN);
      float h  = hfin[(size_t)i*C + c];       // tail rows read adjacent ws: safe
      float ho = (1.f - z)*nn + z*h;
      us hob = f2bf(ho);
      if constexpr (COMPUTE_M)
        tile[(dr+r)*TST + c] = hob;
      if (i < n){
        hfout[(size_t)i*C + c] = ho;
        hbout[(size_t)i*C + c] = hob;
      }
    }
  }
  if constexpr (COMPUTE_M){
    __syncthreads();
    f4_t macc[CT];
    #pragma unroll
    for (int t=0;t<CT;t++) macc[t] = f4_t{0.f,0.f,0.f,0.f};
    #pragma unroll
    for (int ks=0; ks<KS; ks++){
      int k0 = ks*32 + lk;
      bf8_t a = *(const bf8_t*)(tile + lr*TST + k0);
      #pragma unroll
      for (int t=0;t<CT;t++){
        bf8_t b = *(const bf8_t*)(Wtb_next + (size_t)(t*16+lr)*C + k0);
        macc[t] = __builtin_amdgcn_mfma_f32_16x16x32_bf16(a, b, macc[t], 0, 0, 0);
      }
    }
    #pragma unroll
    for (int t=0;t<CT;t++){
      #pragma unroll
      for (int r=0;r<4;r++){
        int node = mbase + dr + r;
        if (node < n)
          mbout[(size_t)node*C + t*16 + lr] = f2bf(macc[t][r]);
      }
    }
  }
}

// ---------------- head via MFMA: elu -> fc1 -> elu -> fc2 -> log_softmax ----
__global__ __launch_bounds__(256) void head_mfma(const float* __restrict__ h2,
    const us* __restrict__ fc1wb, const float* __restrict__ fc1b,
    const us* __restrict__ fc2wpb, const float* __restrict__ fc2bp,
    float* __restrict__ out, int n){
  __shared__ __align__(16) us lds[4][16*136];
  int l = threadIdx.x & 63, w = threadIdx.x >> 6;
  int mbase = blockIdx.x*64 + w*16;          // no early return: barrier stays uniform
  int lr = l & 15, lk = (l >> 4)*8;
  int dr = (l>>4)*4;
  // ---- fc1 ----
  f4_t acc1[8];
  #pragma unroll
  for (int t=0;t<8;t++) acc1[t] = f4_t{0.f,0.f,0.f,0.f};
  #pragma unroll
  for (int ks=0; ks<2; ks++){
    int k0 = ks*32 + lk;
    const float* hp = h2 + (size_t)(mbase+lr)*64 + k0;   // tail rows read scratch: safe
    float4 v0 = *(const float4*)hp;
    float4 v1 = *(const float4*)(hp+4);
    bf8_t a;
    a[0]=(short)f2bf(eluf_(v0.x)); a[1]=(short)f2bf(eluf_(v0.y));
    a[2]=(short)f2bf(eluf_(v0.z)); a[3]=(short)f2bf(eluf_(v0.w));
    a[4]=(short)f2bf(eluf_(v1.x)); a[5]=(short)f2bf(eluf_(v1.y));
    a[6]=(short)f2bf(eluf_(v1.z)); a[7]=(short)f2bf(eluf_(v1.w));
    #pragma unroll
    for (int t=0;t<8;t++){
      bf8_t b = *(const bf8_t*)(fc1wb + (size_t)(t*16+lr)*64 + k0);
      acc1[t] = __builtin_amdgcn_mfma_f32_16x16x32_bf16(a, b, acc1[t], 0, 0, 0);
    }
  }
  // ---- bias + elu, transpose through LDS ----
  us* tile = lds[w];
  #pragma unroll
  for (int t=0;t<8;t++){
    float b1 = fc1b[t*16 + lr];
    #pragma unroll
    for (int r=0;r<4;r++)
      tile[(dr+r)*136 + t*16 + lr] = f2bf(eluf_(acc1[t][r] + b1));
  }
  __syncthreads();
  // ---- fc2 ----
  f4_t acc2 = f4_t{0.f,0.f,0.f,0.f};
  #pragma unroll
  for (int ks=0; ks<4; ks++){
    int k0 = ks*32 + lk;
    bf8_t a = *(const bf8_t*)(tile + lr*136 + k0);
    bf8_t b = *(const bf8_t*)(fc2wpb + (size_t)lr*128 + k0);
    acc2 = __builtin_amdgcn_mfma_f32_16x16x32_bf16(a, b, acc2, 0, 0, 0);
  }
  // ---- log_softmax over classes (16 lanes = 16 cols, 10 valid) ----
  float b2 = fc2bp[lr];
  #pragma unroll
  for (int r=0;r<4;r++){
    float val = acc2[r] + b2;
    float vm = (lr < 10) ? val : -__builtin_inff();
    #pragma unroll
    for (int m=1;m<16;m<<=1) vm = fmaxf(vm, __shfl_xor(vm, m, 64));
    float ex = (lr < 10) ? expf(val - vm) : 0.f;
    #pragma unroll
    for (int m=1;m<16;m<<=1) ex += __shfl_xor(ex, m, 64);
    float lse = vm + logf(ex);
    int node = mbase + dr + r;
    if (lr < 10 && node < n) out[(size_t)node*10 + lr] = val - lse;
  }
}

extern "C" void kernel_launch(void* const* d_in, const int* in_sizes, int n_in,
                              void* d_out, int out_size, void* d_ws, size_t ws_size,
                              hipStream_t stream){
  const float* x    = (const float*)d_in[0];
  const int*   ei   = (const int*)  d_in[1];
  const float* ea   = (const float*)d_in[2];
  const float* W1   = (const float*)d_in[3];
  const float* Wih1 = (const float*)d_in[4];
  const float* Whh1 = (const float*)d_in[5];
  const float* bih1 = (const float*)d_in[6];
  const float* bhh1 = (const float*)d_in[7];
  const float* W2   = (const float*)d_in[8];
  const float* Wih2 = (const float*)d_in[9];
  const float* Whh2 = (const float*)d_in[10];
  const float* bih2 = (const float*)d_in[11];
  const float* bhh2 = (const float*)d_in[12];
  const float* fc1w = (const float*)d_in[13];
  const float* fc1b = (const float*)d_in[14];
  const float* fc2w = (const float*)d_in[15];
  const float* fc2b = (const float*)d_in[16];
  float* outp = (float*)d_out;

  char* ws = (char*)d_ws;
  size_t off = 0;
  auto alloc = [&](size_t bytes)->void*{
    void* p = ws + off;
    off += (bytes + 255) & ~size_t(255);
    return p;
  };
  float* hA   = (float*)alloc(sizeof(float)*N_NODES*32);
  float* hB   = (float*)alloc(sizeof(float)*N_NODES*64);
  us* hAb0    = (us*)alloc(sizeof(us)*N_NODES*32);
  us* hAb1    = (us*)alloc(sizeof(us)*N_NODES*32);
  us* hBb0    = (us*)alloc(sizeof(us)*N_NODES*64);
  us* hBb1    = (us*)alloc(sizeof(us)*N_NODES*64);
  us* mb      = (us*)alloc(sizeof(us)*N_NODES*64);
  us* aggb    = (us*)alloc(sizeof(us)*N_NODES*64);
  int* row_start = (int*)alloc(sizeof(int)*(N_NODES+1));
  int* cnt    = (int*)alloc(sizeof(int)*N_NODES);
  int* cur    = (int*)alloc(sizeof(int)*N_NODES);
  int* pre    = (int*)alloc(sizeof(int)*N_NODES);
  int* bsum   = (int*)alloc(sizeof(int)*1024);
  long long* esrc = (long long*)alloc(sizeof(long long)*N_EDGES);
  us* Wihb1   = (us*)alloc(sizeof(us)*96*32);
  us* Whhb1   = (us*)alloc(sizeof(us)*96*32);
  us* Wihb2   = (us*)alloc(sizeof(us)*192*64);
  us* Whhb2   = (us*)alloc(sizeof(us)*192*64);
  us* Wtb1    = (us*)alloc(sizeof(us)*3*32*32);
  us* Wtb2    = (us*)alloc(sizeof(us)*3*64*64);
  us* fc1wb   = (us*)alloc(sizeof(us)*128*64);
  us* fc2wpb  = (us*)alloc(sizeof(us)*16*128);
  float* fc2bp= (float*)alloc(sizeof(float)*16);
  (void)ws_size; (void)in_sizes; (void)n_in; (void)out_size;

  const int n = N_NODES, e = N_EDGES;
  const int nb = (n + SCAN_BS - 1)/SCAN_BS;
  const int gblk = (n + 63)/64;             // 1563

  // fused weight prep: 56336 elements
  prep_all<<<(56336+255)/256,256,0,stream>>>(Wih1, Whh1, Wih2, Whh2, W1, W2,
      fc1w, fc2w, fc2b, Wihb1, Whhb1, Wihb2, Whhb2, Wtb1, Wtb2, fc1wb, fc2wpb, fc2bp);

  // CSR build
  zero_counts<<<(n+255)/256,256,0,stream>>>(cnt, cur, n);
  count_kernel<<<(e+255)/256,256,0,stream>>>(ei, cnt, e);
  scan1_kernel<<<nb,SCAN_BS,0,stream>>>(cnt, pre, bsum, n);
  scan2_kernel<<<1,1024,0,stream>>>(bsum, nb);
  scan3_kernel<<<(n+255)/256,256,0,stream>>>(pre, bsum, row_start, n);
  scatter_kernel<<<(e/2+255)/256,256,0,stream>>>(ei, ea, row_start, cur, esrc, e);

  // layer 1 (C=32)
  pad_x_kernel<<<(n*32+255)/256,256,0,stream>>>(x, hA, hAb0, n);
  {
    us* c0 = hAb0; us* c1 = hAb1;
    mgemm_mfma<32><<<gblk,256,0,stream>>>(c0, Wtb1, mb, n);
    for (int i=0;i<3;i++){
      agg_kernel<32><<<((long long)n*4+255)/256,256,0,stream>>>(mb, row_start, esrc, aggb, n);
      if (i < 2)
        gru_mfma<32,true><<<gblk,256,0,stream>>>(aggb, c0, hA, Wihb1, Whhb1, bih1, bhh1,
                                                 Wtb1 + (i+1)*32*32, hA, c1, mb, n);
      else
        gru_mfma<32,false><<<gblk,256,0,stream>>>(aggb, c0, hA, Wihb1, Whhb1, bih1, bhh1,
                                                  nullptr, hA, c1, nullptr, n);
      us* t = c0; c0 = c1; c1 = t;
    }
  }

  transition_kernel<<<(n*64+255)/256,256,0,stream>>>(hA, hB, hBb0, n);

  // layer 2 (C=64)
  {
    us* c0 = hBb0; us* c1 = hBb1;
    mgemm_mfma<64><<<gblk,256,0,stream>>>(c0, Wtb2, mb, n);
    for (int i=0;i<3;i++){
      agg_kernel<64><<<((long long)n*8+255)/256,256,0,stream>>>(mb, row_start, esrc, aggb, n);
      if (i < 2)
        gru_mfma<64,true><<<gblk,256,0,stream>>>(aggb, c0, hB, Wihb2, Whhb2, bih2, bhh2,
                                                 Wtb2 + (i+1)*64*64, hB, c1, mb, n);
      else
        gru_mfma<64,false><<<gblk,256,0,stream>>>(aggb, c0, hB, Wihb2, Whhb2, bih2, bhh2,
                                                  nullptr, hB, c1, nullptr, n);
      us* t = c0; c0 = c1; c1 = t;
    }
  }

  head_mfma<<<gblk,256,0,stream>>>(hB, fc1wb, fc1b, fc2wpb, fc2bp, outp, n);
}

// Round 14
// 675.013 us; speedup vs baseline: 4.7443x; 1.0616x over previous
//
#include <hip/hip_runtime.h>
#include <math.h>

#define N_NODES 100000
#define N_EDGES 1600000
#define SCAN_BS 1024
#define NBK 8              // src buckets (src>>14): 16384 nodes = 2MB of m @C=64
#define BKSH 14
#define NBINS (N_NODES*NBK)

typedef __attribute__((ext_vector_type(8))) short bf8_t;   // 8 bf16 in 4 VGPRs
typedef __attribute__((ext_vector_type(4))) float f4_t;
typedef unsigned short us;

__device__ __forceinline__ float sigmoidf_(float x){ return 1.f/(1.f + expf(-x)); }
__device__ __forceinline__ float eluf_(float x){ return x > 0.f ? x : expm1f(x); }
__device__ __forceinline__ us f2bf(float x){
  unsigned u = __float_as_uint(x);
  unsigned r = u + 0x7FFFu + ((u>>16)&1u);
  return (us)(r>>16);
}
__device__ __forceinline__ float bf2f(us v){
  return __uint_as_float(((unsigned)v)<<16);
}

// ---------------- fused weight prep (one kernel, segment-dispatched) ----------
__global__ void prep_all(const float* __restrict__ Wih1, const float* __restrict__ Whh1,
                         const float* __restrict__ Wih2, const float* __restrict__ Whh2,
                         const float* __restrict__ W1,   const float* __restrict__ W2,
                         const float* __restrict__ fc1w, const float* __restrict__ fc2w,
                         const float* __restrict__ fc2b,
                         us* Wihb1, us* Whhb1, us* Wihb2, us* Whhb2,
                         us* Wtb1, us* Wtb2, us* fc1wb, us* fc2wpb, float* fc2bp){
  int i = blockIdx.x*256 + threadIdx.x;
  if (i < 3072) { Wihb1[i]=f2bf(Wih1[i]); return; } i -= 3072;
  if (i < 3072) { Whhb1[i]=f2bf(Whh1[i]); return; } i -= 3072;
  if (i < 12288){ Wihb2[i]=f2bf(Wih2[i]); return; } i -= 12288;
  if (i < 12288){ Whhb2[i]=f2bf(Whh2[i]); return; } i -= 12288;
  if (i < 3072) { int k=i%32, c=(i/32)%32, m=i/1024;           // Wt[m][c][k] = W[m][k][c]
                  Wtb1[i]=f2bf(W1[m*1024 + k*32 + c]); return; } i -= 3072;
  if (i < 12288){ int k=i%64, c=(i/64)%64, m=i/4096;
                  Wtb2[i]=f2bf(W2[m*4096 + k*64 + c]); return; } i -= 12288;
  if (i < 8192) { fc1wb[i]=f2bf(fc1w[i]); return; } i -= 8192;
  if (i < 2048) { int c=i/128, k=i%128;
                  fc2wpb[i]=(c<10)?f2bf(fc2w[c*128+k]):(us)0; return; } i -= 2048;
  if (i < 16)   { fc2bp[i] = (i<10)? fc2b[i] : 0.f; }
}

// ---------------- bucketed CSR build: key = dst*NBK + (src>>BKSH) ----------
__global__ void zero_counts(int* cnt, int* cur, int n){
  int i = blockIdx.x*blockDim.x + threadIdx.x;
  if (i < n){ cnt[i]=0; cur[i]=0; }
}
__global__ void count_kernel(const int* __restrict__ ei, int* __restrict__ cnt, int e){
  int i = blockIdx.x*blockDim.x + threadIdx.x;
  if (i < e){
    int s = ei[i], d = ei[N_EDGES + i];
    atomicAdd(&cnt[d*NBK + (s>>BKSH)], 1);
  }
}
__global__ void scan1_kernel(const int* __restrict__ cnt, int* __restrict__ pre,
                             int* __restrict__ bsum, int n){
  __shared__ int sh[SCAN_BS];
  int t = threadIdx.x, gi = blockIdx.x*SCAN_BS + t;
  int v = (gi < n) ? cnt[gi] : 0;
  sh[t] = v;
  __syncthreads();
  for (int off=1; off<SCAN_BS; off<<=1){
    int u = (t>=off)?sh[t-off]:0;
    __syncthreads();
    sh[t] += u;
    __syncthreads();
  }
  if (gi < n) pre[gi] = sh[t] - v;
  if (t == SCAN_BS-1) bsum[blockIdx.x] = sh[t];
}
__global__ void scan2_kernel(int* __restrict__ bsum, int nb){
  __shared__ int sh[1024];
  int t = threadIdx.x;
  int v = (t < nb) ? bsum[t] : 0;
  sh[t] = v;
  __syncthreads();
  for (int off=1; off<1024; off<<=1){
    int u = (t>=off)?sh[t-off]:0;
    __syncthreads();
    sh[t] += u;
    __syncthreads();
  }
  if (t < nb) bsum[t] = sh[t] - v;
}
__global__ void scan3_kernel(const int* __restrict__ pre, const int* __restrict__ bsum,
                             int* __restrict__ rs2, int total){
  int i = blockIdx.x*blockDim.x + threadIdx.x;
  if (i < total) rs2[i] = pre[i] + bsum[i/SCAN_BS];
  if (i == 0) rs2[total] = N_EDGES;
}
// 2 edges/thread, nontemporal packed store; bucket-grouped destinations
__global__ void scatter_kernel(const int* __restrict__ ei, const float* __restrict__ ea,
    const int* __restrict__ rs2, int* __restrict__ cur,
    long long* __restrict__ esrc, int e){
  int i0 = (blockIdx.x*blockDim.x + threadIdx.x)*2;
  #pragma unroll
  for (int j=0;j<2;j++){
    int i = i0 + j;
    if (i < e){
      int s = ei[i], d = ei[N_EDGES + i];
      int bin = d*NBK + (s>>BKSH);
      int p = rs2[bin] + atomicAdd(&cur[bin], 1);
      long long v = (long long)(unsigned)s
                  | ((long long)(unsigned)__float_as_int(ea[i]) << 32);
      __builtin_nontemporal_store(v, &esrc[p]);
    }
  }
}

// ---------------- elementwise ----------------
__global__ void pad_x_kernel(const float* __restrict__ x, float* __restrict__ h,
                             us* __restrict__ hb, int n){
  int i = blockIdx.x*blockDim.x + threadIdx.x;
  if (i < n*32){
    int node = i >> 5, c = i & 31;
    float v = (c < 16) ? x[node*16 + c] : 0.f;
    h[i] = v;
    hb[i] = f2bf(v);
  }
}
__global__ void transition_kernel(const float* __restrict__ h1, float* __restrict__ h2,
                                  us* __restrict__ h2b, int n){
  int i = blockIdx.x*blockDim.x + threadIdx.x;
  if (i < n*64){
    int node = i >> 6, c = i & 63;
    float v = (c < 32) ? eluf_(h1[node*32 + c]) : 0.f;
    h2[i] = v;
    h2b[i] = f2bf(v);
  }
}

// ---------------- m = h @ W via MFMA (layer-start only) ----------------
template<int C>
__global__ __launch_bounds__(256) void mgemm_mfma(const us* __restrict__ hb,
    const us* __restrict__ Wtb, us* __restrict__ mb, int n){
  constexpr int NT = C/16, KS = C/32;
  int l = threadIdx.x & 63, w = threadIdx.x >> 6;
  int mbase = blockIdx.x*64 + w*16;
  if (mbase >= n) return;
  int lr = l & 15, lk = (l >> 4)*8;
  f4_t acc[NT];
  #pragma unroll
  for (int t=0;t<NT;t++) acc[t] = f4_t{0.f,0.f,0.f,0.f};
  #pragma unroll
  for (int ks=0; ks<KS; ks++){
    int k0 = ks*32 + lk;
    bf8_t a = *(const bf8_t*)(hb + (size_t)(mbase+lr)*C + k0);
    #pragma unroll
    for (int t=0;t<NT;t++){
      bf8_t b = *(const bf8_t*)(Wtb + (size_t)(t*16+lr)*C + k0);
      acc[t] = __builtin_amdgcn_mfma_f32_16x16x32_bf16(a, b, acc[t], 0, 0, 0);
    }
  }
  int dr = (l>>4)*4;
  #pragma unroll
  for (int t=0;t<NT;t++){
    #pragma unroll
    for (int r=0;r<4;r++){
      int node = mbase + dr + r;
      if (node < n)
        mb[(size_t)node*C + t*16 + lr] = f2bf(acc[t][r]);
    }
  }
}

// ---------------- agg: 8 channels/lane via uint4 gathers, 4-deep pipeline ----
// Edge list is (dst, src-bucket)-sorted: all threads sweep src ranges roughly
// in step -> instantaneous working set ~2 buckets (~4MB) -> L2-resident repeats.
template<int C>
__global__ void agg_kernel(const us* __restrict__ mb, const int* __restrict__ rs2,
    const long long* __restrict__ esrc, us* __restrict__ aggb, int n_nodes){
  constexpr int GPN = C/8;
  int gid = blockIdx.x*blockDim.x + threadIdx.x;
  int nn = gid / GPN, g8 = gid % GPN;
  if (nn >= n_nodes) return;
  int s = rs2[nn*NBK], e = rs2[nn*NBK + NBK];
  float acc[8];
  #pragma unroll
  for (int j=0;j<8;j++) acc[j] = -__builtin_inff();
  const us* mbg = mb + g8*8;
  int i = s;
  for (; i+4<=e; i+=4){
    long long e0 = esrc[i], e1 = esrc[i+1], e2 = esrc[i+2], e3 = esrc[i+3];
    uint4 v0 = *(const uint4*)(mbg + (size_t)(unsigned)(e0 & 0xFFFFFFFF)*C);
    uint4 v1 = *(const uint4*)(mbg + (size_t)(unsigned)(e1 & 0xFFFFFFFF)*C);
    uint4 v2 = *(const uint4*)(mbg + (size_t)(unsigned)(e2 & 0xFFFFFFFF)*C);
    uint4 v3 = *(const uint4*)(mbg + (size_t)(unsigned)(e3 & 0xFFFFFFFF)*C);
    float w0 = __int_as_float((int)(e0>>32)), w1 = __int_as_float((int)(e1>>32));
    float w2 = __int_as_float((int)(e2>>32)), w3 = __int_as_float((int)(e3>>32));
    unsigned a0[4] = {v0.x, v0.y, v0.z, v0.w};
    unsigned a1[4] = {v1.x, v1.y, v1.z, v1.w};
    unsigned a2[4] = {v2.x, v2.y, v2.z, v2.w};
    unsigned a3[4] = {v3.x, v3.y, v3.z, v3.w};
    #pragma unroll
    for (int q=0;q<4;q++){
      float x0 = fmaxf(__uint_as_float(a0[q]<<16)*w0, __uint_as_float(a1[q]<<16)*w1);
      float x1 = fmaxf(__uint_as_float(a2[q]<<16)*w2, __uint_as_float(a3[q]<<16)*w3);
      float y0 = fmaxf(__uint_as_float(a0[q]&0xFFFF0000u)*w0, __uint_as_float(a1[q]&0xFFFF0000u)*w1);
      float y1 = fmaxf(__uint_as_float(a2[q]&0xFFFF0000u)*w2, __uint_as_float(a3[q]&0xFFFF0000u)*w3);
      acc[2*q]   = fmaxf(acc[2*q],   fmaxf(x0, x1));
      acc[2*q+1] = fmaxf(acc[2*q+1], fmaxf(y0, y1));
    }
  }
  for (; i<e; i++){
    long long e0 = esrc[i];
    uint4 v0 = *(const uint4*)(mbg + (size_t)(unsigned)(e0 & 0xFFFFFFFF)*C);
    float w0 = __int_as_float((int)(e0>>32));
    unsigned a0[4] = {v0.x, v0.y, v0.z, v0.w};
    #pragma unroll
    for (int q=0;q<4;q++){
      acc[2*q]   = fmaxf(acc[2*q],   __uint_as_float(a0[q]<<16)*w0);
      acc[2*q+1] = fmaxf(acc[2*q+1], __uint_as_float(a0[q]&0xFFFF0000u)*w0);
    }
  }
  unsigned r[8];
  #pragma unroll
  for (int j=0;j<8;j++) r[j] = (e > s) ? (unsigned)f2bf(acc[j]) : 0u;
  uint4 o;
  o.x = r[0] | (r[1]<<16); o.y = r[2] | (r[3]<<16);
  o.z = r[4] | (r[5]<<16); o.w = r[6] | (r[7]<<16);
  *(uint4*)(aggb + (size_t)nn*C + g8*8) = o;
}

// ---------------- fused GRU via MFMA; optionally computes next-iter m ------
template<int C, bool COMPUTE_M>
__global__ __launch_bounds__(256) void gru_mfma(
    const us* __restrict__ aggb, const us* __restrict__ hbin,
    const float* __restrict__ hfin,
    const us* __restrict__ Wihb, const us* __restrict__ Whhb,
    const float* __restrict__ bih, const float* __restrict__ bhh,
    const us* __restrict__ Wtb_next,
    float* __restrict__ hfout, us* __restrict__ hbout, us* __restrict__ mbout, int n){
  constexpr int NT = 3*C/16;
  constexpr int KS = C/32;
  constexpr int CT = C/16;
  constexpr int TST = C + 8;                     // LDS tile stride (bf16)
  constexpr int TSZ = COMPUTE_M ? 16*TST : 1;
  __shared__ us tlds[4][TSZ];
  int l = threadIdx.x & 63, w = threadIdx.x >> 6;
  int mbase = blockIdx.x*64 + w*16;
  int lr = l & 15, lk = (l >> 4)*8;
  f4_t accI[NT], accH[NT];
  #pragma unroll
  for (int t=0;t<NT;t++){ accI[t]=f4_t{0.f,0.f,0.f,0.f}; accH[t]=f4_t{0.f,0.f,0.f,0.f}; }
  #pragma unroll
  for (int ks=0; ks<KS; ks++){
    int k0 = ks*32 + lk;
    bf8_t aI = *(const bf8_t*)(aggb + (size_t)(mbase+lr)*C + k0);
    bf8_t aH = *(const bf8_t*)(hbin + (size_t)(mbase+lr)*C + k0);
    #pragma unroll
    for (int t=0;t<NT;t++){
      bf8_t bI = *(const bf8_t*)(Wihb + (size_t)(t*16+lr)*C + k0);
      accI[t] = __builtin_amdgcn_mfma_f32_16x16x32_bf16(aI, bI, accI[t], 0, 0, 0);
      bf8_t bH = *(const bf8_t*)(Whhb + (size_t)(t*16+lr)*C + k0);
      accH[t] = __builtin_amdgcn_mfma_f32_16x16x32_bf16(aH, bH, accH[t], 0, 0, 0);
    }
  }
  int dr = (l>>4)*4;
  us* tile = tlds[w];
  #pragma unroll
  for (int ct=0; ct<CT; ct++){
    int c = ct*16 + lr;
    float bR = bih[c],     cR = bhh[c];
    float bZ = bih[c+C],   cZ = bhh[c+C];
    float bN = bih[c+2*C], cN = bhh[c+2*C];
    #pragma unroll
    for (int r=0;r<4;r++){
      int i = mbase + dr + r;
      float giR = accI[ct][r] + bR,      ghR = accH[ct][r] + cR;
      float giZ = accI[CT+ct][r] + bZ,   ghZ = accH[CT+ct][r] + cZ;
      float giN = accI[2*CT+ct][r] + bN, ghN = accH[2*CT+ct][r] + cN;
      float rr = sigmoidf_(giR + ghR);
      float z  = sigmoidf_(giZ + ghZ);
      float nn = tanhf(giN + rr*ghN);
      float h  = hfin[(size_t)i*C + c];       // tail rows read adjacent ws: safe
      float ho = (1.f - z)*nn + z*h;
      us hob = f2bf(ho);
      if constexpr (COMPUTE_M)
        tile[(dr+r)*TST + c] = hob;
      if (i < n){
        hfout[(size_t)i*C + c] = ho;
        hbout[(size_t)i*C + c] = hob;
      }
    }
  }
  if constexpr (COMPUTE_M){
    __syncthreads();
    f4_t macc[CT];
    #pragma unroll
    for (int t=0;t<CT;t++) macc[t] = f4_t{0.f,0.f,0.f,0.f};
    #pragma unroll
    for (int ks=0; ks<KS; ks++){
      int k0 = ks*32 + lk;
      bf8_t a = *(const bf8_t*)(tile + lr*TST + k0);
      #pragma unroll
      for (int t=0;t<CT;t++){
        bf8_t b = *(const bf8_t*)(Wtb_next + (size_t)(t*16+lr)*C + k0);
        macc[t] = __builtin_amdgcn_mfma_f32_16x16x32_bf16(a, b, macc[t], 0, 0, 0);
      }
    }
    #pragma unroll
    for (int t=0;t<CT;t++){
      #pragma unroll
      for (int r=0;r<4;r++){
        int node = mbase + dr + r;
        if (node < n)
          mbout[(size_t)node*C + t*16 + lr] = f2bf(macc[t][r]);
      }
    }
  }
}

// ---------------- head via MFMA: elu -> fc1 -> elu -> fc2 -> log_softmax ----
__global__ __launch_bounds__(256) void head_mfma(const float* __restrict__ h2,
    const us* __restrict__ fc1wb, const float* __restrict__ fc1b,
    const us* __restrict__ fc2wpb, const float* __restrict__ fc2bp,
    float* __restrict__ out, int n){
  __shared__ __align__(16) us lds[4][16*136];
  int l = threadIdx.x & 63, w = threadIdx.x >> 6;
  int mbase = blockIdx.x*64 + w*16;          // no early return: barrier stays uniform
  int lr = l & 15, lk = (l >> 4)*8;
  int dr = (l>>4)*4;
  // ---- fc1 ----
  f4_t acc1[8];
  #pragma unroll
  for (int t=0;t<8;t++) acc1[t] = f4_t{0.f,0.f,0.f,0.f};
  #pragma unroll
  for (int ks=0; ks<2; ks++){
    int k0 = ks*32 + lk;
    const float* hp = h2 + (size_t)(mbase+lr)*64 + k0;   // tail rows read scratch: safe
    float4 v0 = *(const float4*)hp;
    float4 v1 = *(const float4*)(hp+4);
    bf8_t a;
    a[0]=(short)f2bf(eluf_(v0.x)); a[1]=(short)f2bf(eluf_(v0.y));
    a[2]=(short)f2bf(eluf_(v0.z)); a[3]=(short)f2bf(eluf_(v0.w));
    a[4]=(short)f2bf(eluf_(v1.x)); a[5]=(short)f2bf(eluf_(v1.y));
    a[6]=(short)f2bf(eluf_(v1.z)); a[7]=(short)f2bf(eluf_(v1.w));
    #pragma unroll
    for (int t=0;t<8;t++){
      bf8_t b = *(const bf8_t*)(fc1wb + (size_t)(t*16+lr)*64 + k0);
      acc1[t] = __builtin_amdgcn_mfma_f32_16x16x32_bf16(a, b, acc1[t], 0, 0, 0);
    }
  }
  // ---- bias + elu, transpose through LDS ----
  us* tile = lds[w];
  #pragma unroll
  for (int t=0;t<8;t++){
    float b1 = fc1b[t*16 + lr];
    #pragma unroll
    for (int r=0;r<4;r++)
      tile[(dr+r)*136 + t*16 + lr] = f2bf(eluf_(acc1[t][r] + b1));
  }
  __syncthreads();
  // ---- fc2 ----
  f4_t acc2 = f4_t{0.f,0.f,0.f,0.f};
  #pragma unroll
  for (int ks=0; ks<4; ks++){
    int k0 = ks*32 + lk;
    bf8_t a = *(const bf8_t*)(tile + lr*136 + k0);
    bf8_t b = *(const bf8_t*)(fc2wpb + (size_t)lr*128 + k0);
    acc2 = __builtin_amdgcn_mfma_f32_16x16x32_bf16(a, b, acc2, 0, 0, 0);
  }
  // ---- log_softmax over classes (16 lanes = 16 cols, 10 valid) ----
  float b2 = fc2bp[lr];
  #pragma unroll
  for (int r=0;r<4;r++){
    float val = acc2[r] + b2;
    float vm = (lr < 10) ? val : -__builtin_inff();
    #pragma unroll
    for (int m=1;m<16;m<<=1) vm = fmaxf(vm, __shfl_xor(vm, m, 64));
    float ex = (lr < 10) ? expf(val - vm) : 0.f;
    #pragma unroll
    for (int m=1;m<16;m<<=1) ex += __shfl_xor(ex, m, 64);
    float lse = vm + logf(ex);
    int node = mbase + dr + r;
    if (lr < 10 && node < n) out[(size_t)node*10 + lr] = val - lse;
  }
}

extern "C" void kernel_launch(void* const* d_in, const int* in_sizes, int n_in,
                              void* d_out, int out_size, void* d_ws, size_t ws_size,
                              hipStream_t stream){
  const float* x    = (const float*)d_in[0];
  const int*   ei   = (const int*)  d_in[1];
  const float* ea   = (const float*)d_in[2];
  const float* W1   = (const float*)d_in[3];
  const float* Wih1 = (const float*)d_in[4];
  const float* Whh1 = (const float*)d_in[5];
  const float* bih1 = (const float*)d_in[6];
  const float* bhh1 = (const float*)d_in[7];
  const float* W2   = (const float*)d_in[8];
  const float* Wih2 = (const float*)d_in[9];
  const float* Whh2 = (const float*)d_in[10];
  const float* bih2 = (const float*)d_in[11];
  const float* bhh2 = (const float*)d_in[12];
  const float* fc1w = (const float*)d_in[13];
  const float* fc1b = (const float*)d_in[14];
  const float* fc2w = (const float*)d_in[15];
  const float* fc2b = (const float*)d_in[16];
  float* outp = (float*)d_out;

  char* ws = (char*)d_ws;
  size_t off = 0;
  auto alloc = [&](size_t bytes)->void*{
    void* p = ws + off;
    off += (bytes + 255) & ~size_t(255);
    return p;
  };
  float* hA   = (float*)alloc(sizeof(float)*N_NODES*32);
  float* hB   = (float*)alloc(sizeof(float)*N_NODES*64);
  us* hAb0    = (us*)alloc(sizeof(us)*N_NODES*32);
  us* hAb1    = (us*)alloc(sizeof(us)*N_NODES*32);
  us* hBb0    = (us*)alloc(sizeof(us)*N_NODES*64);
  us* hBb1    = (us*)alloc(sizeof(us)*N_NODES*64);
  us* mb      = (us*)alloc(sizeof(us)*N_NODES*64);
  us* aggb    = (us*)alloc(sizeof(us)*N_NODES*64);
  int* rs2    = (int*)alloc(sizeof(int)*(NBINS+1));
  int* cnt    = (int*)alloc(sizeof(int)*NBINS);
  int* cur    = (int*)alloc(sizeof(int)*NBINS);
  int* pre    = (int*)alloc(sizeof(int)*NBINS);
  int* bsum   = (int*)alloc(sizeof(int)*1024);
  long long* esrc = (long long*)alloc(sizeof(long long)*N_EDGES);
  us* Wihb1   = (us*)alloc(sizeof(us)*96*32);
  us* Whhb1   = (us*)alloc(sizeof(us)*96*32);
  us* Wihb2   = (us*)alloc(sizeof(us)*192*64);
  us* Whhb2   = (us*)alloc(sizeof(us)*192*64);
  us* Wtb1    = (us*)alloc(sizeof(us)*3*32*32);
  us* Wtb2    = (us*)alloc(sizeof(us)*3*64*64);
  us* fc1wb   = (us*)alloc(sizeof(us)*128*64);
  us* fc2wpb  = (us*)alloc(sizeof(us)*16*128);
  float* fc2bp= (float*)alloc(sizeof(float)*16);
  (void)ws_size; (void)in_sizes; (void)n_in; (void)out_size;

  const int n = N_NODES, e = N_EDGES;
  const int nbk = (NBINS + SCAN_BS - 1)/SCAN_BS;    // 782 <= 1024 (scan2 limit)
  const int gblk = (n + 63)/64;                      // 1563

  // fused weight prep: 56336 elements
  prep_all<<<(56336+255)/256,256,0,stream>>>(Wih1, Whh1, Wih2, Whh2, W1, W2,
      fc1w, fc2w, fc2b, Wihb1, Whhb1, Wihb2, Whhb2, Wtb1, Wtb2, fc1wb, fc2wpb, fc2bp);

  // bucketed CSR build
  zero_counts<<<(NBINS+255)/256,256,0,stream>>>(cnt, cur, NBINS);
  count_kernel<<<(e+255)/256,256,0,stream>>>(ei, cnt, e);
  scan1_kernel<<<nbk,SCAN_BS,0,stream>>>(cnt, pre, bsum, NBINS);
  scan2_kernel<<<1,1024,0,stream>>>(bsum, nbk);
  scan3_kernel<<<(NBINS+255)/256,256,0,stream>>>(pre, bsum, rs2, NBINS);
  scatter_kernel<<<(e/2+255)/256,256,0,stream>>>(ei, ea, rs2, cur, esrc, e);

  // layer 1 (C=32)
  pad_x_kernel<<<(n*32+255)/256,256,0,stream>>>(x, hA, hAb0, n);
  {
    us* c0 = hAb0; us* c1 = hAb1;
    mgemm_mfma<32><<<gblk,256,0,stream>>>(c0, Wtb1, mb, n);
    for (int i=0;i<3;i++){
      agg_kernel<32><<<((long long)n*4+255)/256,256,0,stream>>>(mb, rs2, esrc, aggb, n);
      if (i < 2)
        gru_mfma<32,true><<<gblk,256,0,stream>>>(aggb, c0, hA, Wihb1, Whhb1, bih1, bhh1,
                                                 Wtb1 + (i+1)*32*32, hA, c1, mb, n);
      else
        gru_mfma<32,false><<<gblk,256,0,stream>>>(aggb, c0, hA, Wihb1, Whhb1, bih1, bhh1,
                                                  nullptr, hA, c1, nullptr, n);
      us* t = c0; c0 = c1; c1 = t;
    }
  }

  transition_kernel<<<(n*64+255)/256,256,0,stream>>>(hA, hB, hBb0, n);

  // layer 2 (C=64)
  {
    us* c0 = hBb0; us* c1 = hBb1;
    mgemm_mfma<64><<<gblk,256,0,stream>>>(c0, Wtb2, mb, n);
    for (int i=0;i<3;i++){
      agg_kernel<64><<<((long long)n*8+255)/256,256,0,stream>>>(mb, rs2, esrc, aggb, n);
      if (i < 2)
        gru_mfma<64,true><<<gblk,256,0,stream>>>(aggb, c0, hB, Wihb2, Whhb2, bih2, bhh2,
                                                 Wtb2 + (i+1)*64*64, hB, c1, mb, n);
      else
        gru_mfma<64,false><<<gblk,256,0,stream>>>(aggb, c0, hB, Wihb2, Whhb2, bih2, bhh2,
                                                  nullptr, hB, c1, nullptr, n);
      us* t = c0; c0 = c1; c1 = t;
    }
  }

  head_mfma<<<gblk,256,0,stream>>>(hB, fc1wb, fc1b, fc2wpb, fc2bp, outp, n);
}